// Round 13
// baseline (177.929 us; speedup 1.0000x reference)
//
#include <hip/hip_runtime.h>
#include <stdint.h>

typedef unsigned short u16;
typedef __bf16 bf16x8 __attribute__((ext_vector_type(8)));
typedef float f32x4 __attribute__((ext_vector_type(4)));

#define CB   2
#define CLQ  2048
#define CLK  2048
#define CHID 1024
#define CNH  16
#define CHD  64

__device__ __forceinline__ u16 f2bf(float x) {
  union { float f; uint32_t u; } c; c.f = x;
  uint32_t r = c.u + 0x7FFFu + ((c.u >> 16) & 1u);
  return (u16)(r >> 16);
}

__device__ __forceinline__ uint32_t cvtpk(float lo, float hi) {
  uint32_t r;
  asm("v_cvt_pk_bf16_f32 %0, %1, %2" : "=v"(r) : "v"(lo), "v"(hi));
  return r;
}

union u4bf8 { uint4 u; bf16x8 v; };

typedef __attribute__((address_space(3))) uint32_t lds_u32;
typedef const __attribute__((address_space(1))) uint32_t glb_u32;
__device__ __forceinline__ void gload16(const void* g, void* l) {
  __builtin_amdgcn_global_load_lds((glb_u32*)g, (lds_u32*)l, 16, 0, 0);
}

// ================= prep megakernel bodies =================
union PrepSmem {
  float t[64][65];
  struct { int bnd[2048]; int part[256]; } ps;
};

__device__ void cvt_body(const float* __restrict__ in, u16* __restrict__ out, int bid) {
  int i = (bid * 256 + (int)threadIdx.x) * 4;
  float4 v = *(const float4*)(in + i);
  ushort4 o;
  o.x = f2bf(v.x); o.y = f2bf(v.y); o.z = f2bf(v.z); o.w = f2bf(v.w);
  *(ushort4*)(out + i) = o;
}

__device__ void wtrans_body(const float* __restrict__ W, u16* __restrict__ WT,
                            int K, int N, int nb, int kb, PrepSmem& sm) {
  const int tx = threadIdx.x & 63, ty = threadIdx.x >> 6;
#pragma unroll
  for (int i = 0; i < 16; i++) {
    int r = i * 4 + ty;
    sm.t[r][tx] = W[(size_t)(kb + r) * N + nb + tx];
  }
  __syncthreads();
#pragma unroll
  for (int i = 0; i < 16; i++) {
    int r = i * 4 + ty;
    WT[(size_t)(nb + r) * K + kb + tx] = f2bf(sm.t[tx][r]);
  }
}

__device__ void pos_seg_body(const int* __restrict__ lengths, const float* __restrict__ dists,
                             float* __restrict__ pos, float* __restrict__ maskv,
                             float* __restrict__ distout, int L, int isKV, int b, PrepSmem& sm) {
  const int tid = threadIdx.x;
  const int* len = lengths + (size_t)b * L;
  int loc[8];
  const int base = tid * 8;
  int s = 0;
#pragma unroll
  for (int i = 0; i < 8; i++) { loc[i] = len[base + i]; s += loc[i]; }
  sm.ps.part[tid] = s;
  __syncthreads();
  for (int off = 1; off < 256; off <<= 1) {
    int v = sm.ps.part[tid];
    int add = (tid >= off) ? sm.ps.part[tid - off] : 0;
    __syncthreads();
    sm.ps.part[tid] = v + add;
    __syncthreads();
  }
  int run = (tid > 0) ? sm.ps.part[tid - 1] : 0;
#pragma unroll
  for (int i = 0; i < 8; i++) { run += loc[i]; sm.ps.bnd[base + i] = run; }
  __syncthreads();
  const int total = sm.ps.bnd[L - 1];
  for (int t = tid; t < L; t += 256) {
    int lo = 0, hi = L;
    while (lo < hi) { int mid = (lo + hi) >> 1; if (sm.ps.bnd[mid] <= t) lo = mid + 1; else hi = mid; }
    int seg = lo < L - 1 ? lo : L - 1;
    int start = sm.ps.bnd[seg] - len[seg];
    bool valid = t < total;
    pos[(size_t)b * L + t] = valid ? (float)(t - start) : 0.0f;
    if (isKV) {
      maskv[(size_t)b * L + t] = valid ? 0.0f : -1e9f;
      distout[(size_t)b * L + t] = valid ? dists[(size_t)b * L + seg] : 0.0f;
    } else {
      maskv[(size_t)b * L + t] = valid ? 1.0f : 0.0f;
    }
  }
}

// grid 9220: [0,4096) cvt QS | [4096,8192) cvt KVS | [8192,8448) wtrans Wq |
// [8448,8960) wtrans Wkv | [8960,9216) wtrans Wo | [9216,9220) pos_seg
__global__ __launch_bounds__(256) void prep_kernel(
    const float* q_states, const float* kv_states,
    const float* Wq, const float* Wkv, const float* Wo,
    const int* mq, const int* mkv, const float* dists,
    u16* QS, u16* KVS, u16* WqT, u16* WkvT, u16* WoT,
    float* posq, float* vq, float* posk, float* kbias, float* dtok)
{
  __shared__ PrepSmem psm;
  const int bid = blockIdx.x;
  if (bid < 4096) {
    cvt_body(q_states, QS, bid);
  } else if (bid < 8192) {
    cvt_body(kv_states, KVS, bid - 4096);
  } else if (bid < 8448) {
    int x = bid - 8192;
    wtrans_body(Wq, WqT, 1024, 1024, (x & 15) * 64, (x >> 4) * 64, psm);
  } else if (bid < 8960) {
    int x = bid - 8448;
    wtrans_body(Wkv, WkvT, 1024, 2048, (x & 31) * 64, (x >> 5) * 64, psm);
  } else if (bid < 9216) {
    int x = bid - 8960;
    wtrans_body(Wo, WoT, 1024, 1024, (x & 15) * 64, (x >> 4) * 64, psm);
  } else {
    int x = bid - 9216;
    if (x < 2) pos_seg_body(mq, nullptr, posq, vq, nullptr, 2048, 0, x, psm);
    else       pos_seg_body(mkv, dists, posk, kbias, dtok, 2048, 1, x - 2, psm);
  }
}

// ================= MFMA GEMM body (BK=64, single-buffered) =================
union GemmSmem {
  struct { u16 As[128 * 64]; u16 Bs[128 * 64]; } st;
  u16 tr[4][64 * 72];                 // MODE1 V-transpose epilogue buffers
};

template<int MODE>
__device__ void gemm_body(GemmSmem& sm,
    const u16* __restrict__ A, const u16* __restrict__ WT, const float* __restrict__ bias,
    int M, int N, int K, const float* __restrict__ pos, const float* __restrict__ dist,
    int bx, int by, u16* __restrict__ outA, u16* __restrict__ outB, float* __restrict__ outF)
{
  const int rowbase = by * 128;
  const int colbase = bx * 128;
  const int tid = threadIdx.x;
  const int lane = tid & 63, wv = tid >> 6;
  const int wr = wv >> 1, wc = wv & 1;
  const int l15 = lane & 15, l4 = lane >> 4;
  const int l8r = lane >> 3;                // row-within-8 for staging
  const int sjc = (lane & 7) ^ l8r;         // swizzled source chunk (involution)
  f32x4 acc[4][4] = {};
  for (int kt = 0; kt < K; kt += 64) {
    __syncthreads();
#pragma unroll
    for (int i = 0; i < 4; i++) {
      int rg = (wv * 4 + i) * 8 + l8r;      // 0..127
      gload16(A  + (size_t)(rowbase + rg) * K + kt + sjc * 8, &sm.st.As[(wv * 4 + i) * 512]);
      gload16(WT + (size_t)(colbase + rg) * K + kt + sjc * 8, &sm.st.Bs[(wv * 4 + i) * 512]);
    }
    __syncthreads();
#pragma unroll
    for (int kk = 0; kk < 2; kk++) {
      bf16x8 af[4], bfr[4];
      const int fsw = l15 & 7;
#pragma unroll
      for (int m = 0; m < 4; m++)
        af[m] = *(const bf16x8*)&sm.st.As[(wr * 64 + m * 16 + l15) * 64 + (((kk * 4 + l4) ^ fsw) * 8)];
#pragma unroll
      for (int n = 0; n < 4; n++)
        bfr[n] = *(const bf16x8*)&sm.st.Bs[(wc * 64 + n * 16 + l15) * 64 + (((kk * 4 + l4) ^ fsw) * 8)];
#pragma unroll
      for (int m = 0; m < 4; m++)
#pragma unroll
        for (int n = 0; n < 4; n++)
          acc[m][n] = __builtin_amdgcn_mfma_f32_16x16x32_bf16(af[m], bfr[n], acc[m][n], 0, 0, 0);
    }
  }
  __syncthreads();

  if constexpr (MODE == 2) {
#pragma unroll
    for (int n = 0; n < 4; n++) {
      float bv = bias[colbase + wc * 64 + n * 16 + l15];
#pragma unroll
      for (int m = 0; m < 4; m++)
#pragma unroll
        for (int r = 0; r < 4; r++) {
          int grow = rowbase + wr * 64 + m * 16 + l4 * 4 + r;
          outF[(size_t)grow * N + colbase + wc * 64 + n * 16 + l15] = acc[m][n][r] + bv;
        }
    }
  } else if constexpr (MODE == 0) {
    const int b = rowbase >> 11;
    const int h = (colbase + wc * 64) >> 6;
    const float if0 = __powf(10000.0f, -(float)l15 / 32.0f);
    const float if1 = __powf(10000.0f, -(float)(16 + l15) / 32.0f);
    const float b0 = bias[colbase + wc * 64 + l15];
    const float b1 = bias[colbase + wc * 64 + 16 + l15];
    const float b2 = bias[colbase + wc * 64 + 32 + l15];
    const float b3 = bias[colbase + wc * 64 + 48 + l15];
#pragma unroll
    for (int m = 0; m < 4; m++) {
#pragma unroll
      for (int r = 0; r < 4; r++) {
        int grow = rowbase + wr * 64 + m * 16 + l4 * 4 + r;
        int tok = grow & 2047;
        float pv = pos[grow];
        float s0, c0, s1, c1;
        __sincosf(pv * if0, &s0, &c0);
        __sincosf(pv * if1, &s1, &c1);
        float x0 = (acc[m][0][r] + b0) * 0.125f;
        float x1 = (acc[m][1][r] + b1) * 0.125f;
        float x2 = (acc[m][2][r] + b2) * 0.125f;
        float x3 = (acc[m][3][r] + b3) * 0.125f;
        size_t ob = (((size_t)b * CNH + h) * CLQ + tok) * CHD;
        outA[ob + l15]      = f2bf(x0 * c0 - x2 * s0);
        outA[ob + 32 + l15] = f2bf(x2 * c0 + x0 * s0);
        outA[ob + 16 + l15] = f2bf(x1 * c1 - x3 * s1);
        outA[ob + 48 + l15] = f2bf(x3 * c1 + x1 * s1);
      }
    }
  } else {  // MODE 1
    const int b = rowbase >> 11;
    if (colbase < CHID) {   // K half
      const int h = (colbase + wc * 64) >> 6;
      const float if0 = __powf(10000.0f, -(float)l15 / 32.0f);
      const float if1 = __powf(10000.0f, -(float)(16 + l15) / 32.0f);
      const float df0 = __expf(-11.5129254f + 0.32666551f * (float)l15);
      const float df1 = __expf(-11.5129254f + 0.32666551f * (float)(16 + l15));
      const float b0 = bias[colbase + wc * 64 + l15];
      const float b1 = bias[colbase + wc * 64 + 16 + l15];
      const float b2 = bias[colbase + wc * 64 + 32 + l15];
      const float b3 = bias[colbase + wc * 64 + 48 + l15];
#pragma unroll
      for (int m = 0; m < 4; m++) {
#pragma unroll
        for (int r = 0; r < 4; r++) {
          int grow = rowbase + wr * 64 + m * 16 + l4 * 4 + r;
          int tok = grow & 2047;
          float pv = pos[grow];
          float dv = dist[grow];
          float s0, c0, s1, c1, ds0, dc0, ds1, dc1;
          __sincosf(pv * if0, &s0, &c0);
          __sincosf(pv * if1, &s1, &c1);
          __sincosf(dv * df0, &ds0, &dc0);
          __sincosf(dv * df1, &ds1, &dc1);
          float x0 = acc[m][0][r] + b0;
          float x1 = acc[m][1][r] + b1;
          float x2 = acc[m][2][r] + b2;
          float x3 = acc[m][3][r] + b3;
          size_t ob = (((size_t)b * CNH + h) * CLK + tok) * CHD;
          outA[ob + l15]      = f2bf(x0 * c0 - x2 * s0 + dc0);
          outA[ob + 32 + l15] = f2bf(x2 * c0 + x0 * s0 + ds0);
          outA[ob + 16 + l15] = f2bf(x1 * c1 - x3 * s1 + dc1);
          outA[ob + 48 + l15] = f2bf(x3 * c1 + x1 * s1 + ds1);
        }
      }
    } else {                // V half -> write transposed [B,NH,HD,LK]
      const int h = (colbase + wc * 64 - CHID) >> 6;
      const int tokb = (rowbase & 2047) + wr * 64;
      u16* T = sm.tr[wv];
#pragma unroll
      for (int n = 0; n < 4; n++) {
        float bv = bias[colbase + wc * 64 + n * 16 + l15];
#pragma unroll
        for (int m = 0; m < 4; m++)
#pragma unroll
          for (int r = 0; r < 4; r++)
            T[(n * 16 + l15) * 72 + m * 16 + l4 * 4 + r] = f2bf(acc[m][n][r] + bv);
      }
#pragma unroll
      for (int p = 0; p < 8; p++) {
        int c = p * 64 + lane;
        int hd = c >> 3, to = (c & 7) * 8;
        *(bf16x8*)(outB + (((size_t)b * CNH + h) * CHD + hd) * CLK + tokb + to) =
            *(const bf16x8*)&T[hd * 72 + to];
      }
    }
  }
}

// fused qproj + kvproj: grid (24, 32); bx<8 -> qproj col bx, else kvproj col bx-8
__global__ __launch_bounds__(256) void qkv_kernel(
    const u16* QS, const u16* WqT, const float* bq, const float* posq,
    const u16* KVS, const u16* WkvT, const float* bkv, const float* posk, const float* dtok,
    u16* QROT, u16* KROT, u16* VT)
{
  __shared__ __align__(16) GemmSmem sm;
  if (blockIdx.x < 8)
    gemm_body<0>(sm, QS, WqT, bq, 4096, 1024, 1024, posq, nullptr,
                 blockIdx.x, blockIdx.y, QROT, nullptr, nullptr);
  else
    gemm_body<1>(sm, KVS, WkvT, bkv, 4096, 2048, 1024, posk, dtok,
                 blockIdx.x - 8, blockIdx.y, KROT, VT, nullptr);
}

__global__ __launch_bounds__(256) void oproj_kernel(
    const u16* AOUT, const u16* WoT, const float* bo, float* out)
{
  __shared__ __align__(16) GemmSmem sm;
  gemm_body<2>(sm, AOUT, WoT, bo, 4096, 1024, 1024, nullptr, nullptr,
               blockIdx.x, blockIdx.y, nullptr, nullptr, out);
}

// ---------------- flash attention: 4-wave QBLK=64 (occupancy via grid) ----------------
// Grid (32,16,2) = 1024 blocks x 4 waves = exactly 4 blocks/CU (LDS 40960B),
// 16 waves/CU. Block structure and staging byte-identical to passing R11;
// per-wave code is R11's m=0 slice (16 q-rows/wave). P^T pack stride 72->64
// u32 and epilogue stride 36->32 to fit the 40960B LDS budget (both bijective).
__global__ __launch_bounds__(256) void attn_kernel(
    const u16* __restrict__ qr, const u16* __restrict__ kr, const u16* __restrict__ vt,
    const float* __restrict__ kbias, const float* __restrict__ validq,
    u16* __restrict__ aout)
{
  __shared__ __align__(16) u16 Ks[2][64 * 64];       // [tok][hd], swizzled 128B rows
  __shared__ __align__(16) u16 Vs[2][64 * 64];       // [hd][tok], swizzled 128B rows
  __shared__ __align__(16) uint32_t Pb32[4][512];    // per-wave P^T bounce (u32-typed)
  const int qb = blockIdx.x * 64;
  const int h = blockIdx.y, b = blockIdx.z;
  const int tid = threadIdx.x, lane = tid & 63, wv = tid >> 6;
  const int l15 = lane & 15, l4 = lane >> 4;
  const u16* kg = kr + ((size_t)b * CNH + h) * CLK * CHD;
  const u16* vg = vt + ((size_t)b * CNH + h) * CHD * CLK;
  const float* kb_b = kbias + (size_t)b * CLK;
  const int qrow0 = qb + wv * 16;
  const u16* qg = qr + (((size_t)b * CNH + h) * CLQ + qrow0) * CHD;

  bf16x8 qf[2];
#pragma unroll
  for (int hc = 0; hc < 2; hc++)
    qf[hc] = *(const bf16x8*)(qg + l15 * CHD + hc * 32 + l4 * 8);

  const int srow = lane >> 3;               // 0..7 (row within 1KB region)
  const int sj = (lane & 7) ^ srow;         // swizzled source chunk
  f32x4 accO[4] = {};
  float lReg = 0.f;
  uint32_t* PbW = Pb32[wv];

  // staging byte-identical to R11: wave stages 2 K-regions + 2 V-regions
  auto stage = [&](int buf, int kt) {
#pragma unroll
    for (int i = 0; i < 2; i++) {
      int r = (wv * 2 + i) * 8 + srow;
      gload16(kg + (size_t)(kt + r) * CHD + sj * 8, &Ks[buf][(wv * 2 + i) * 512]);
      gload16(vg + (size_t)r * CLK + kt + sj * 8,   &Vs[buf][(wv * 2 + i) * 512]);
    }
  };

  stage(0, 0);
  __syncthreads();
  for (int t = 0; t < CLK / 64; t++) {
    const int cur = t & 1;
    if (t < CLK / 64 - 1) stage(cur ^ 1, (t + 1) * 64);
    const u16* Kc = Ks[cur];
    const u16* Vc = Vs[cur];
    const int fsw = l15 & 7;
    float4 kb4[4];
#pragma unroll
    for (int c = 0; c < 4; c++)
      kb4[c] = *(const float4*)(kb_b + t * 64 + c * 16 + l4 * 4);
    bf16x8 kf[4][2], vf[4][2];
#pragma unroll
    for (int c = 0; c < 4; c++)
#pragma unroll
      for (int hc = 0; hc < 2; hc++)
        kf[c][hc] = *(const bf16x8*)&Kc[(c * 16 + l15) * 64 + (((hc * 4 + l4) ^ fsw) * 8)];
#pragma unroll
    for (int hh = 0; hh < 4; hh++)
#pragma unroll
      for (int kc = 0; kc < 2; kc++)
        vf[hh][kc] = *(const bf16x8*)&Vc[(hh * 16 + l15) * 64 + (((kc * 4 + l4) ^ fsw) * 8)];

    // S^T = K @ Q : lane owns q=l15, kv = c*16 + l4*4 + r
    float p[16];
#pragma unroll
    for (int c = 0; c < 4; c++) {
      f32x4 z = {};
      z = __builtin_amdgcn_mfma_f32_16x16x32_bf16(kf[c][0], qf[0], z, 0, 0, 0);
      z = __builtin_amdgcn_mfma_f32_16x16x32_bf16(kf[c][1], qf[1], z, 0, 0, 0);
      const float* kbp = (const float*)&kb4[c];
#pragma unroll
      for (int r = 0; r < 4; r++)
        p[c * 4 + r] = __expf(z[r] + kbp[r]);   // no-max softmax (R6/R8/R11-verified)
    }
    lReg += (((p[0] + p[1]) + (p[2] + p[3])) + ((p[4] + p[5]) + (p[6] + p[7]))) +
            (((p[8] + p[9]) + (p[10] + p[11])) + ((p[12] + p[13]) + (p[14] + p[15])));
    // pack P^T in PV B-frag order: kv-block t8 at bijective 256B (=64 u32) stride
    const int wbase = 2 * (l4 & 1);
    asm volatile("" ::: "memory");
#pragma unroll
    for (int c = 0; c < 4; c++) {
      int t8 = 2 * c + (l4 >> 1);
#pragma unroll
      for (int rr = 0; rr < 2; rr++)
        PbW[t8 * 64 + l15 * 4 + wbase + rr] = cvtpk(p[c * 4 + 2 * rr], p[c * 4 + 2 * rr + 1]);
    }
    asm volatile("" ::: "memory");
    u4bf8 plo, phi;
    plo.u = *(const uint4*)&PbW[l4 * 64 + l15 * 4];
    phi.u = *(const uint4*)&PbW[256 + l4 * 64 + l15 * 4];
#pragma unroll
    for (int hh = 0; hh < 4; hh++) {
      accO[hh] = __builtin_amdgcn_mfma_f32_16x16x32_bf16(vf[hh][0], plo.v, accO[hh], 0, 0, 0);
      accO[hh] = __builtin_amdgcn_mfma_f32_16x16x32_bf16(vf[hh][1], phi.v, accO[hh], 0, 0, 0);
    }
    asm volatile("" ::: "memory");
    __syncthreads();
  }

  // epilogue: normalize, bounce through LDS (u32-typed) for coalesced stores
  float lq = lReg;
  lq += __shfl_xor(lq, 16);
  lq += __shfl_xor(lq, 32);
  float inv = validq[(size_t)b * CLQ + qrow0 + l15] / lq;
  asm volatile("" ::: "memory");
#pragma unroll
  for (int hh = 0; hh < 4; hh++)
#pragma unroll
    for (int rr = 0; rr < 2; rr++)
      PbW[l15 * 32 + hh * 8 + l4 * 2 + rr] =
          cvtpk(accO[hh][2 * rr] * inv, accO[hh][2 * rr + 1] * inv);
  asm volatile("" ::: "memory");
#pragma unroll
  for (int i = 0; i < 2; i++) {
    int row = i * 8 + (lane >> 3), ch = lane & 7;
    u4bf8 ov;
    ov.u = *(const uint4*)&PbW[row * 32 + ch * 4];
    *(bf16x8*)(aout + ((size_t)b * CLQ + qrow0 + row) * CHID + h * CHD + ch * 8) = ov.v;
  }
}

extern "C" void kernel_launch(void* const* d_in, const int* in_sizes, int n_in,
                              void* d_out, int out_size, void* d_ws, size_t ws_size,
                              hipStream_t stream)
{
  const float* q_states  = (const float*)d_in[0];
  const float* kv_states = (const float*)d_in[1];
  const float* dists     = (const float*)d_in[2];
  const int*   mq        = (const int*)d_in[3];
  const int*   mkv       = (const int*)d_in[4];
  const float* Wq        = (const float*)d_in[5];
  const float* bq        = (const float*)d_in[6];
  const float* Wkv       = (const float*)d_in[7];
  const float* bkv       = (const float*)d_in[8];
  const float* Wo        = (const float*)d_in[9];
  const float* bo        = (const float*)d_in[10];
  float* out = (float*)d_out;

  char* w = (char*)d_ws;
  auto alloc = [&](size_t bytes) {
    char* p = w;
    w += (bytes + 255) & ~(size_t)255;
    return p;
  };
  u16* WqT  = (u16*)alloc((size_t)1024 * 1024 * 2);
  u16* WkvT = (u16*)alloc((size_t)2048 * 1024 * 2);
  u16* WoT  = (u16*)alloc((size_t)1024 * 1024 * 2);
  u16* QS   = (u16*)alloc((size_t)4096 * 1024 * 2);
  u16* KVS  = (u16*)alloc((size_t)4096 * 1024 * 2);
  u16* QROT = (u16*)alloc((size_t)4096 * 1024 * 2);
  u16* KROT = (u16*)alloc((size_t)4096 * 1024 * 2);
  u16* VT   = (u16*)alloc((size_t)4096 * 1024 * 2);
  u16* AOUT = (u16*)alloc((size_t)4096 * 1024 * 2);
  float* posq  = (float*)alloc(4096 * 4);
  float* vq    = (float*)alloc(4096 * 4);
  float* posk  = (float*)alloc(4096 * 4);
  float* kbias = (float*)alloc(4096 * 4);
  float* dtok  = (float*)alloc(4096 * 4);

  prep_kernel<<<9220, 256, 0, stream>>>(q_states, kv_states, Wq, Wkv, Wo,
                                        mq, mkv, dists,
                                        QS, KVS, WqT, WkvT, WoT,
                                        posq, vq, posk, kbias, dtok);
  qkv_kernel<<<dim3(24, 32), 256, 0, stream>>>(QS, WqT, bq, posq,
                                               KVS, WkvT, bkv, posk, dtok,
                                               QROT, KROT, VT);
  attn_kernel<<<dim3(32, 16, 2), 256, 0, stream>>>(QROT, KROT, VT, kbias, vq, AOUT);
  oproj_kernel<<<dim3(8, 32), 256, 0, stream>>>(AOUT, WoT, bo, out);
}

// Round 15
// 164.154 us; speedup vs baseline: 1.0839x; 1.0839x over previous
//
#include <hip/hip_runtime.h>
#include <stdint.h>

typedef unsigned short u16;
typedef __bf16 bf16x8 __attribute__((ext_vector_type(8)));
typedef float f32x4 __attribute__((ext_vector_type(4)));

#define CB   2
#define CLQ  2048
#define CLK  2048
#define CHID 1024
#define CNH  16
#define CHD  64

__device__ __forceinline__ u16 f2bf(float x) {
  union { float f; uint32_t u; } c; c.f = x;
  uint32_t r = c.u + 0x7FFFu + ((c.u >> 16) & 1u);
  return (u16)(r >> 16);
}

__device__ __forceinline__ uint32_t cvtpk(float lo, float hi) {
  uint32_t r;
  asm("v_cvt_pk_bf16_f32 %0, %1, %2" : "=v"(r) : "v"(lo), "v"(hi));
  return r;
}

union u4bf8 { uint4 u; bf16x8 v; };

typedef __attribute__((address_space(3))) uint32_t lds_u32;
typedef const __attribute__((address_space(1))) uint32_t glb_u32;
__device__ __forceinline__ void gload16(const void* g, void* l) {
  __builtin_amdgcn_global_load_lds((glb_u32*)g, (lds_u32*)l, 16, 0, 0);
}

// ================= prep megakernel bodies =================
union PrepSmem {
  float t[64][65];
  struct { int bnd[2048]; int part[256]; } ps;
};

__device__ void cvt_body(const float* __restrict__ in, u16* __restrict__ out, int bid) {
  int i = (bid * 256 + (int)threadIdx.x) * 4;
  float4 v = *(const float4*)(in + i);
  ushort4 o;
  o.x = f2bf(v.x); o.y = f2bf(v.y); o.z = f2bf(v.z); o.w = f2bf(v.w);
  *(ushort4*)(out + i) = o;
}

__device__ void wtrans_body(const float* __restrict__ W, u16* __restrict__ WT,
                            int K, int N, int nb, int kb, PrepSmem& sm) {
  const int tx = threadIdx.x & 63, ty = threadIdx.x >> 6;
#pragma unroll
  for (int i = 0; i < 16; i++) {
    int r = i * 4 + ty;
    sm.t[r][tx] = W[(size_t)(kb + r) * N + nb + tx];
  }
  __syncthreads();
#pragma unroll
  for (int i = 0; i < 16; i++) {
    int r = i * 4 + ty;
    WT[(size_t)(nb + r) * K + kb + tx] = f2bf(sm.t[tx][r]);
  }
}

__device__ void pos_seg_body(const int* __restrict__ lengths, const float* __restrict__ dists,
                             float* __restrict__ pos, float* __restrict__ maskv,
                             float* __restrict__ distout, int L, int isKV, int b, PrepSmem& sm) {
  const int tid = threadIdx.x;
  const int* len = lengths + (size_t)b * L;
  int loc[8];
  const int base = tid * 8;
  int s = 0;
#pragma unroll
  for (int i = 0; i < 8; i++) { loc[i] = len[base + i]; s += loc[i]; }
  sm.ps.part[tid] = s;
  __syncthreads();
  for (int off = 1; off < 256; off <<= 1) {
    int v = sm.ps.part[tid];
    int add = (tid >= off) ? sm.ps.part[tid - off] : 0;
    __syncthreads();
    sm.ps.part[tid] = v + add;
    __syncthreads();
  }
  int run = (tid > 0) ? sm.ps.part[tid - 1] : 0;
#pragma unroll
  for (int i = 0; i < 8; i++) { run += loc[i]; sm.ps.bnd[base + i] = run; }
  __syncthreads();
  const int total = sm.ps.bnd[L - 1];
  for (int t = tid; t < L; t += 256) {
    int lo = 0, hi = L;
    while (lo < hi) { int mid = (lo + hi) >> 1; if (sm.ps.bnd[mid] <= t) lo = mid + 1; else hi = mid; }
    int seg = lo < L - 1 ? lo : L - 1;
    int start = sm.ps.bnd[seg] - len[seg];
    bool valid = t < total;
    pos[(size_t)b * L + t] = valid ? (float)(t - start) : 0.0f;
    if (isKV) {
      maskv[(size_t)b * L + t] = valid ? 0.0f : -1e9f;
      distout[(size_t)b * L + t] = valid ? dists[(size_t)b * L + seg] : 0.0f;
    } else {
      maskv[(size_t)b * L + t] = valid ? 1.0f : 0.0f;
    }
  }
}

// grid 9220: [0,4096) cvt QS | [4096,8192) cvt KVS | [8192,8448) wtrans Wq |
// [8448,8960) wtrans Wkv | [8960,9216) wtrans Wo | [9216,9220) pos_seg
__global__ __launch_bounds__(256) void prep_kernel(
    const float* q_states, const float* kv_states,
    const float* Wq, const float* Wkv, const float* Wo,
    const int* mq, const int* mkv, const float* dists,
    u16* QS, u16* KVS, u16* WqT, u16* WkvT, u16* WoT,
    float* posq, float* vq, float* posk, float* kbias, float* dtok)
{
  __shared__ PrepSmem psm;
  const int bid = blockIdx.x;
  if (bid < 4096) {
    cvt_body(q_states, QS, bid);
  } else if (bid < 8192) {
    cvt_body(kv_states, KVS, bid - 4096);
  } else if (bid < 8448) {
    int x = bid - 8192;
    wtrans_body(Wq, WqT, 1024, 1024, (x & 15) * 64, (x >> 4) * 64, psm);
  } else if (bid < 8960) {
    int x = bid - 8448;
    wtrans_body(Wkv, WkvT, 1024, 2048, (x & 31) * 64, (x >> 5) * 64, psm);
  } else if (bid < 9216) {
    int x = bid - 8960;
    wtrans_body(Wo, WoT, 1024, 1024, (x & 15) * 64, (x >> 4) * 64, psm);
  } else {
    int x = bid - 9216;
    if (x < 2) pos_seg_body(mq, nullptr, posq, vq, nullptr, 2048, 0, x, psm);
    else       pos_seg_body(mkv, dists, posk, kbias, dtok, 2048, 1, x - 2, psm);
  }
}

// ================= MFMA GEMM body (BK=64, single-buffered) =================
union GemmSmem {
  struct { u16 As[128 * 64]; u16 Bs[128 * 64]; } st;
  u16 tr[4][64 * 72];                 // MODE1 V-transpose epilogue buffers
};

template<int MODE>
__device__ void gemm_body(GemmSmem& sm,
    const u16* __restrict__ A, const u16* __restrict__ WT, const float* __restrict__ bias,
    int M, int N, int K, const float* __restrict__ pos, const float* __restrict__ dist,
    int bx, int by, u16* __restrict__ outA, u16* __restrict__ outB, float* __restrict__ outF)
{
  const int rowbase = by * 128;
  const int colbase = bx * 128;
  const int tid = threadIdx.x;
  const int lane = tid & 63, wv = tid >> 6;
  const int wr = wv >> 1, wc = wv & 1;
  const int l15 = lane & 15, l4 = lane >> 4;
  const int l8r = lane >> 3;                // row-within-8 for staging
  const int sjc = (lane & 7) ^ l8r;         // swizzled source chunk (involution)
  f32x4 acc[4][4] = {};
  for (int kt = 0; kt < K; kt += 64) {
    __syncthreads();
#pragma unroll
    for (int i = 0; i < 4; i++) {
      int rg = (wv * 4 + i) * 8 + l8r;      // 0..127
      gload16(A  + (size_t)(rowbase + rg) * K + kt + sjc * 8, &sm.st.As[(wv * 4 + i) * 512]);
      gload16(WT + (size_t)(colbase + rg) * K + kt + sjc * 8, &sm.st.Bs[(wv * 4 + i) * 512]);
    }
    __syncthreads();
#pragma unroll
    for (int kk = 0; kk < 2; kk++) {
      bf16x8 af[4], bfr[4];
      const int fsw = l15 & 7;
#pragma unroll
      for (int m = 0; m < 4; m++)
        af[m] = *(const bf16x8*)&sm.st.As[(wr * 64 + m * 16 + l15) * 64 + (((kk * 4 + l4) ^ fsw) * 8)];
#pragma unroll
      for (int n = 0; n < 4; n++)
        bfr[n] = *(const bf16x8*)&sm.st.Bs[(wc * 64 + n * 16 + l15) * 64 + (((kk * 4 + l4) ^ fsw) * 8)];
#pragma unroll
      for (int m = 0; m < 4; m++)
#pragma unroll
        for (int n = 0; n < 4; n++)
          acc[m][n] = __builtin_amdgcn_mfma_f32_16x16x32_bf16(af[m], bfr[n], acc[m][n], 0, 0, 0);
    }
  }
  __syncthreads();

  if constexpr (MODE == 2) {
#pragma unroll
    for (int n = 0; n < 4; n++) {
      float bv = bias[colbase + wc * 64 + n * 16 + l15];
#pragma unroll
      for (int m = 0; m < 4; m++)
#pragma unroll
        for (int r = 0; r < 4; r++) {
          int grow = rowbase + wr * 64 + m * 16 + l4 * 4 + r;
          outF[(size_t)grow * N + colbase + wc * 64 + n * 16 + l15] = acc[m][n][r] + bv;
        }
    }
  } else if constexpr (MODE == 0) {
    const int b = rowbase >> 11;
    const int h = (colbase + wc * 64) >> 6;
    const float if0 = __powf(10000.0f, -(float)l15 / 32.0f);
    const float if1 = __powf(10000.0f, -(float)(16 + l15) / 32.0f);
    const float b0 = bias[colbase + wc * 64 + l15];
    const float b1 = bias[colbase + wc * 64 + 16 + l15];
    const float b2 = bias[colbase + wc * 64 + 32 + l15];
    const float b3 = bias[colbase + wc * 64 + 48 + l15];
    // 0.125 * log2(e): fold exp->exp2 conversion into Q scale (commutes with RoPE)
    const float QS2 = 0.18033688f;
#pragma unroll
    for (int m = 0; m < 4; m++) {
#pragma unroll
      for (int r = 0; r < 4; r++) {
        int grow = rowbase + wr * 64 + m * 16 + l4 * 4 + r;
        int tok = grow & 2047;
        float pv = pos[grow];
        float s0, c0, s1, c1;
        __sincosf(pv * if0, &s0, &c0);
        __sincosf(pv * if1, &s1, &c1);
        float x0 = (acc[m][0][r] + b0) * QS2;
        float x1 = (acc[m][1][r] + b1) * QS2;
        float x2 = (acc[m][2][r] + b2) * QS2;
        float x3 = (acc[m][3][r] + b3) * QS2;
        size_t ob = (((size_t)b * CNH + h) * CLQ + tok) * CHD;
        outA[ob + l15]      = f2bf(x0 * c0 - x2 * s0);
        outA[ob + 32 + l15] = f2bf(x2 * c0 + x0 * s0);
        outA[ob + 16 + l15] = f2bf(x1 * c1 - x3 * s1);
        outA[ob + 48 + l15] = f2bf(x3 * c1 + x1 * s1);
      }
    }
  } else {  // MODE 1
    const int b = rowbase >> 11;
    if (colbase < CHID) {   // K half
      const int h = (colbase + wc * 64) >> 6;
      const float if0 = __powf(10000.0f, -(float)l15 / 32.0f);
      const float if1 = __powf(10000.0f, -(float)(16 + l15) / 32.0f);
      const float df0 = __expf(-11.5129254f + 0.32666551f * (float)l15);
      const float df1 = __expf(-11.5129254f + 0.32666551f * (float)(16 + l15));
      const float b0 = bias[colbase + wc * 64 + l15];
      const float b1 = bias[colbase + wc * 64 + 16 + l15];
      const float b2 = bias[colbase + wc * 64 + 32 + l15];
      const float b3 = bias[colbase + wc * 64 + 48 + l15];
#pragma unroll
      for (int m = 0; m < 4; m++) {
#pragma unroll
        for (int r = 0; r < 4; r++) {
          int grow = rowbase + wr * 64 + m * 16 + l4 * 4 + r;
          int tok = grow & 2047;
          float pv = pos[grow];
          float dv = dist[grow];
          float s0, c0, s1, c1, ds0, dc0, ds1, dc1;
          __sincosf(pv * if0, &s0, &c0);
          __sincosf(pv * if1, &s1, &c1);
          __sincosf(dv * df0, &ds0, &dc0);
          __sincosf(dv * df1, &ds1, &dc1);
          float x0 = acc[m][0][r] + b0;
          float x1 = acc[m][1][r] + b1;
          float x2 = acc[m][2][r] + b2;
          float x3 = acc[m][3][r] + b3;
          size_t ob = (((size_t)b * CNH + h) * CLK + tok) * CHD;
          outA[ob + l15]      = f2bf(x0 * c0 - x2 * s0 + dc0);
          outA[ob + 32 + l15] = f2bf(x2 * c0 + x0 * s0 + ds0);
          outA[ob + 16 + l15] = f2bf(x1 * c1 - x3 * s1 + dc1);
          outA[ob + 48 + l15] = f2bf(x3 * c1 + x1 * s1 + ds1);
        }
      }
    } else {                // V half -> write transposed [B,NH,HD,LK]
      const int h = (colbase + wc * 64 - CHID) >> 6;
      const int tokb = (rowbase & 2047) + wr * 64;
      u16* T = sm.tr[wv];
#pragma unroll
      for (int n = 0; n < 4; n++) {
        float bv = bias[colbase + wc * 64 + n * 16 + l15];
#pragma unroll
        for (int m = 0; m < 4; m++)
#pragma unroll
          for (int r = 0; r < 4; r++)
            T[(n * 16 + l15) * 72 + m * 16 + l4 * 4 + r] = f2bf(acc[m][n][r] + bv);
      }
#pragma unroll
      for (int p = 0; p < 8; p++) {
        int c = p * 64 + lane;
        int hd = c >> 3, to = (c & 7) * 8;
        *(bf16x8*)(outB + (((size_t)b * CNH + h) * CHD + hd) * CLK + tokb + to) =
            *(const bf16x8*)&T[hd * 72 + to];
      }
    }
  }
}

// fused qproj + kvproj: grid (24, 32); bx<8 -> qproj col bx, else kvproj col bx-8
__global__ __launch_bounds__(256) void qkv_kernel(
    const u16* QS, const u16* WqT, const float* bq, const float* posq,
    const u16* KVS, const u16* WkvT, const float* bkv, const float* posk, const float* dtok,
    u16* QROT, u16* KROT, u16* VT)
{
  __shared__ __align__(16) GemmSmem sm;
  if (blockIdx.x < 8)
    gemm_body<0>(sm, QS, WqT, bq, 4096, 1024, 1024, posq, nullptr,
                 blockIdx.x, blockIdx.y, QROT, nullptr, nullptr);
  else
    gemm_body<1>(sm, KVS, WkvT, bkv, 4096, 2048, 1024, posk, dtok,
                 blockIdx.x - 8, blockIdx.y, KROT, VT, nullptr);
}

__global__ __launch_bounds__(256) void oproj_kernel(
    const u16* AOUT, const u16* WoT, const float* bo, float* out)
{
  __shared__ __align__(16) GemmSmem sm;
  gemm_body<2>(sm, AOUT, WoT, bo, 4096, 1024, 1024, nullptr, nullptr,
               blockIdx.x, blockIdx.y, nullptr, nullptr, out);
}

// ---------------- flash attention: R11 geometry + zero in-loop global loads ----------------
// 4 waves x 32 q-rows (QBLK 128), grid (16,16,2). kbias staged to LDS ONCE at
// entry, so the K-loop's only VMEM is the gload_lds prefetch -> it stays in
// flight across the tile's compute (previously the per-tile kbias global load
// forced an early vmcnt drain, serializing the double-buffer). exp2f softmax
// (log2e folded into Q scale); P-pack uses b64 writes. Else byte-identical R11.
__global__ __launch_bounds__(256) void attn_kernel(
    const u16* __restrict__ qr, const u16* __restrict__ kr, const u16* __restrict__ vt,
    const float* __restrict__ kbias, const float* __restrict__ validq,
    u16* __restrict__ aout)
{
  __shared__ __align__(16) u16 Ks[2][64 * 64];       // [tok][hd], swizzled 128B rows
  __shared__ __align__(16) u16 Vs[2][64 * 64];       // [hd][tok], swizzled 128B rows
  __shared__ __align__(16) uint32_t Pb32[4][592];    // per-wave P^T bounce (u32-typed)
  __shared__ __align__(16) float KBs[2048];          // kbias staged once
  const int qb = blockIdx.x * 128;
  const int h = blockIdx.y, b = blockIdx.z;
  const int tid = threadIdx.x, lane = tid & 63, wv = tid >> 6;
  const int l15 = lane & 15, l4 = lane >> 4;
  const u16* kg = kr + ((size_t)b * CNH + h) * CLK * CHD;
  const u16* vg = vt + ((size_t)b * CNH + h) * CHD * CLK;
  const float* kb_b = kbias + (size_t)b * CLK;
  const int qrow0 = qb + wv * 32;
  const u16* qg = qr + (((size_t)b * CNH + h) * CLQ + qrow0) * CHD;

  bf16x8 qf[2][2];
#pragma unroll
  for (int m = 0; m < 2; m++)
#pragma unroll
    for (int hc = 0; hc < 2; hc++)
      qf[m][hc] = *(const bf16x8*)(qg + (m * 16 + l15) * CHD + hc * 32 + l4 * 8);

  const int srow = lane >> 3;               // 0..7 (row within 1KB region)
  const int sj = (lane & 7) ^ srow;         // swizzled source chunk
  f32x4 accO[2][4] = {};
  float lReg[2] = {0.f, 0.f};
  uint32_t* PbW = Pb32[wv];

  auto stage = [&](int buf, int kt) {
#pragma unroll
    for (int i = 0; i < 2; i++) {
      int r = (wv * 2 + i) * 8 + srow;
      gload16(kg + (size_t)(kt + r) * CHD + sj * 8, &Ks[buf][(wv * 2 + i) * 512]);
      gload16(vg + (size_t)r * CLK + kt + sj * 8,   &Vs[buf][(wv * 2 + i) * 512]);
    }
  };

  // one-time kbias stage (8 float4 per thread-slice); covered by the barrier below
#pragma unroll
  for (int i = 0; i < 2; i++) {
    int idx = (i * 256 + tid) * 4;
    *(float4*)&KBs[idx] = *(const float4*)(kb_b + idx);
  }
  stage(0, 0);
  __syncthreads();
  for (int t = 0; t < CLK / 64; t++) {
    const int cur = t & 1;
    if (t < CLK / 64 - 1) stage(cur ^ 1, (t + 1) * 64);
    const u16* Kc = Ks[cur];
    const u16* Vc = Vs[cur];
    const int fsw = l15 & 7;
    float4 kb4[4];
#pragma unroll
    for (int c = 0; c < 4; c++)
      kb4[c] = *(const float4*)&KBs[t * 64 + c * 16 + l4 * 4];
    bf16x8 kf[4][2], vf[4][2];
#pragma unroll
    for (int c = 0; c < 4; c++)
#pragma unroll
      for (int hc = 0; hc < 2; hc++)
        kf[c][hc] = *(const bf16x8*)&Kc[(c * 16 + l15) * 64 + (((hc * 4 + l4) ^ fsw) * 8)];
#pragma unroll
    for (int hh = 0; hh < 4; hh++)
#pragma unroll
      for (int kc = 0; kc < 2; kc++)
        vf[hh][kc] = *(const bf16x8*)&Vc[(hh * 16 + l15) * 64 + (((kc * 4 + l4) ^ fsw) * 8)];
#pragma unroll
    for (int m = 0; m < 2; m++) {
      // S^T = K @ Q : lane owns q=l15, kv = c*16 + l4*4 + r
      float p[16];
#pragma unroll
      for (int c = 0; c < 4; c++) {
        f32x4 z = {};
        z = __builtin_amdgcn_mfma_f32_16x16x32_bf16(kf[c][0], qf[m][0], z, 0, 0, 0);
        z = __builtin_amdgcn_mfma_f32_16x16x32_bf16(kf[c][1], qf[m][1], z, 0, 0, 0);
        const float* kbp = (const float*)&kb4[c];
#pragma unroll
        for (int r = 0; r < 4; r++)
          p[c * 4 + r] = exp2f(z[r] + kbp[r]);  // log2e pre-folded into Q
      }
      lReg[m] += (((p[0] + p[1]) + (p[2] + p[3])) + ((p[4] + p[5]) + (p[6] + p[7]))) +
                 (((p[8] + p[9]) + (p[10] + p[11])) + ((p[12] + p[13]) + (p[14] + p[15])));
      // pack P^T in PV B-frag order: kv-block t8 at bijective 288B (=72 u32) stride
      const int wbase = 2 * (l4 & 1);
      asm volatile("" ::: "memory");
#pragma unroll
      for (int c = 0; c < 4; c++) {
        int t8 = 2 * c + (l4 >> 1);
        uint2 w2;
        w2.x = cvtpk(p[c * 4 + 0], p[c * 4 + 1]);
        w2.y = cvtpk(p[c * 4 + 2], p[c * 4 + 3]);
        *(uint2*)&PbW[t8 * 72 + l15 * 4 + wbase] = w2;
      }
      asm volatile("" ::: "memory");
      u4bf8 plo, phi;
      plo.u = *(const uint4*)&PbW[l4 * 72 + l15 * 4];
      phi.u = *(const uint4*)&PbW[288 + l4 * 72 + l15 * 4];
#pragma unroll
      for (int hh = 0; hh < 4; hh++) {
        accO[m][hh] = __builtin_amdgcn_mfma_f32_16x16x32_bf16(vf[hh][0], plo.v, accO[m][hh], 0, 0, 0);
        accO[m][hh] = __builtin_amdgcn_mfma_f32_16x16x32_bf16(vf[hh][1], phi.v, accO[m][hh], 0, 0, 0);
      }
      asm volatile("" ::: "memory");
    }
    __syncthreads();
  }

  // epilogue: normalize, bounce through LDS (u32-typed) for coalesced stores
#pragma unroll
  for (int m = 0; m < 2; m++) {
    float lq = lReg[m];
    lq += __shfl_xor(lq, 16);
    lq += __shfl_xor(lq, 32);
    float inv = validq[(size_t)b * CLQ + qrow0 + m * 16 + l15] / lq;
    asm volatile("" ::: "memory");
#pragma unroll
    for (int hh = 0; hh < 4; hh++)
#pragma unroll
      for (int rr = 0; rr < 2; rr++)
        PbW[l15 * 36 + hh * 8 + l4 * 2 + rr] =
            cvtpk(accO[m][hh][2 * rr] * inv, accO[m][hh][2 * rr + 1] * inv);
    asm volatile("" ::: "memory");
#pragma unroll
    for (int i = 0; i < 2; i++) {
      int row = i * 8 + (lane >> 3), ch = lane & 7;
      u4bf8 ov;
      ov.u = *(const uint4*)&PbW[row * 36 + ch * 4];
      *(bf16x8*)(aout + ((size_t)b * CLQ + qrow0 + m * 16 + row) * CHID + h * CHD + ch * 8) = ov.v;
    }
    asm volatile("" ::: "memory");
  }
}

extern "C" void kernel_launch(void* const* d_in, const int* in_sizes, int n_in,
                              void* d_out, int out_size, void* d_ws, size_t ws_size,
                              hipStream_t stream)
{
  const float* q_states  = (const float*)d_in[0];
  const float* kv_states = (const float*)d_in[1];
  const float* dists     = (const float*)d_in[2];
  const int*   mq        = (const int*)d_in[3];
  const int*   mkv       = (const int*)d_in[4];
  const float* Wq        = (const float*)d_in[5];
  const float* bq        = (const float*)d_in[6];
  const float* Wkv       = (const float*)d_in[7];
  const float* bkv       = (const float*)d_in[8];
  const float* Wo        = (const float*)d_in[9];
  const float* bo        = (const float*)d_in[10];
  float* out = (float*)d_out;

  char* w = (char*)d_ws;
  auto alloc = [&](size_t bytes) {
    char* p = w;
    w += (bytes + 255) & ~(size_t)255;
    return p;
  };
  u16* WqT  = (u16*)alloc((size_t)1024 * 1024 * 2);
  u16* WkvT = (u16*)alloc((size_t)2048 * 1024 * 2);
  u16* WoT  = (u16*)alloc((size_t)1024 * 1024 * 2);
  u16* QS   = (u16*)alloc((size_t)4096 * 1024 * 2);
  u16* KVS  = (u16*)alloc((size_t)4096 * 1024 * 2);
  u16* QROT = (u16*)alloc((size_t)4096 * 1024 * 2);
  u16* KROT = (u16*)alloc((size_t)4096 * 1024 * 2);
  u16* VT   = (u16*)alloc((size_t)4096 * 1024 * 2);
  u16* AOUT = (u16*)alloc((size_t)4096 * 1024 * 2);
  float* posq  = (float*)alloc(4096 * 4);
  float* vq    = (float*)alloc(4096 * 4);
  float* posk  = (float*)alloc(4096 * 4);
  float* kbias = (float*)alloc(4096 * 4);
  float* dtok  = (float*)alloc(4096 * 4);

  prep_kernel<<<9220, 256, 0, stream>>>(q_states, kv_states, Wq, Wkv, Wo,
                                        mq, mkv, dists,
                                        QS, KVS, WqT, WkvT, WoT,
                                        posq, vq, posk, kbias, dtok);
  qkv_kernel<<<dim3(24, 32), 256, 0, stream>>>(QS, WqT, bq, posq,
                                               KVS, WkvT, bkv, posk, dtok,
                                               QROT, KROT, VT);
  attn_kernel<<<dim3(16, 16, 2), 256, 0, stream>>>(QROT, KROT, VT, kbias, vq, AOUT);
  oproj_kernel<<<dim3(8, 32), 256, 0, stream>>>(AOUT, WoT, bo, out);
}

// Round 17
// 151.174 us; speedup vs baseline: 1.1770x; 1.0859x over previous
//
#include <hip/hip_runtime.h>
#include <stdint.h>

typedef unsigned short u16;
typedef __bf16 bf16x8 __attribute__((ext_vector_type(8)));
typedef float f32x4 __attribute__((ext_vector_type(4)));

#define CB   2
#define CLQ  2048
#define CLK  2048
#define CHID 1024
#define CNH  16
#define CHD  64

__device__ __forceinline__ u16 f2bf(float x) {
  union { float f; uint32_t u; } c; c.f = x;
  uint32_t r = c.u + 0x7FFFu + ((c.u >> 16) & 1u);
  return (u16)(r >> 16);
}

__device__ __forceinline__ uint32_t cvtpk(float lo, float hi) {
  uint32_t r;
  asm("v_cvt_pk_bf16_f32 %0, %1, %2" : "=v"(r) : "v"(lo), "v"(hi));
  return r;
}

__device__ __forceinline__ float fexp2(float x) {   // raw v_exp_f32 (2^x), fast path
  float r;
  asm("v_exp_f32 %0, %1" : "=v"(r) : "v"(x));
  return r;
}

union u4bf8 { uint4 u; bf16x8 v; };

typedef __attribute__((address_space(3))) uint32_t lds_u32;
typedef const __attribute__((address_space(1))) uint32_t glb_u32;
__device__ __forceinline__ void gload16(const void* g, void* l) {
  __builtin_amdgcn_global_load_lds((glb_u32*)g, (lds_u32*)l, 16, 0, 0);
}

// ================= prep megakernel bodies =================
union PrepSmem {
  float t[64][65];
  struct { int bnd[2048]; int part[256]; } ps;
};

__device__ void cvt_body(const float* __restrict__ in, u16* __restrict__ out, int bid) {
  int i = (bid * 256 + (int)threadIdx.x) * 4;
  float4 v = *(const float4*)(in + i);
  ushort4 o;
  o.x = f2bf(v.x); o.y = f2bf(v.y); o.z = f2bf(v.z); o.w = f2bf(v.w);
  *(ushort4*)(out + i) = o;
}

__device__ void wtrans_body(const float* __restrict__ W, u16* __restrict__ WT,
                            int K, int N, int nb, int kb, PrepSmem& sm) {
  const int tx = threadIdx.x & 63, ty = threadIdx.x >> 6;
#pragma unroll
  for (int i = 0; i < 16; i++) {
    int r = i * 4 + ty;
    sm.t[r][tx] = W[(size_t)(kb + r) * N + nb + tx];
  }
  __syncthreads();
#pragma unroll
  for (int i = 0; i < 16; i++) {
    int r = i * 4 + ty;
    WT[(size_t)(nb + r) * K + kb + tx] = f2bf(sm.t[tx][r]);
  }
}

__device__ void pos_seg_body(const int* __restrict__ lengths, const float* __restrict__ dists,
                             float* __restrict__ pos, float* __restrict__ maskv,
                             float* __restrict__ distout, int L, int isKV, int b, PrepSmem& sm) {
  const int tid = threadIdx.x;
  const int* len = lengths + (size_t)b * L;
  int loc[8];
  const int base = tid * 8;
  int s = 0;
#pragma unroll
  for (int i = 0; i < 8; i++) { loc[i] = len[base + i]; s += loc[i]; }
  sm.ps.part[tid] = s;
  __syncthreads();
  for (int off = 1; off < 256; off <<= 1) {
    int v = sm.ps.part[tid];
    int add = (tid >= off) ? sm.ps.part[tid - off] : 0;
    __syncthreads();
    sm.ps.part[tid] = v + add;
    __syncthreads();
  }
  int run = (tid > 0) ? sm.ps.part[tid - 1] : 0;
#pragma unroll
  for (int i = 0; i < 8; i++) { run += loc[i]; sm.ps.bnd[base + i] = run; }
  __syncthreads();
  const int total = sm.ps.bnd[L - 1];
  for (int t = tid; t < L; t += 256) {
    int lo = 0, hi = L;
    while (lo < hi) { int mid = (lo + hi) >> 1; if (sm.ps.bnd[mid] <= t) lo = mid + 1; else hi = mid; }
    int seg = lo < L - 1 ? lo : L - 1;
    int start = sm.ps.bnd[seg] - len[seg];
    bool valid = t < total;
    pos[(size_t)b * L + t] = valid ? (float)(t - start) : 0.0f;
    if (isKV) {
      maskv[(size_t)b * L + t] = valid ? 0.0f : -1e9f;
      distout[(size_t)b * L + t] = valid ? dists[(size_t)b * L + seg] : 0.0f;
    } else {
      maskv[(size_t)b * L + t] = valid ? 1.0f : 0.0f;
    }
  }
}

// grid 9220: [0,4096) cvt QS | [4096,8192) cvt KVS | [8192,8448) wtrans Wq |
// [8448,8960) wtrans Wkv | [8960,9216) wtrans Wo | [9216,9220) pos_seg
__global__ __launch_bounds__(256) void prep_kernel(
    const float* q_states, const float* kv_states,
    const float* Wq, const float* Wkv, const float* Wo,
    const int* mq, const int* mkv, const float* dists,
    u16* QS, u16* KVS, u16* WqT, u16* WkvT, u16* WoT,
    float* posq, float* vq, float* posk, float* kbias, float* dtok)
{
  __shared__ PrepSmem psm;
  const int bid = blockIdx.x;
  if (bid < 4096) {
    cvt_body(q_states, QS, bid);
  } else if (bid < 8192) {
    cvt_body(kv_states, KVS, bid - 4096);
  } else if (bid < 8448) {
    int x = bid - 8192;
    wtrans_body(Wq, WqT, 1024, 1024, (x & 15) * 64, (x >> 4) * 64, psm);
  } else if (bid < 8960) {
    int x = bid - 8448;
    wtrans_body(Wkv, WkvT, 1024, 2048, (x & 31) * 64, (x >> 5) * 64, psm);
  } else if (bid < 9216) {
    int x = bid - 8960;
    wtrans_body(Wo, WoT, 1024, 1024, (x & 15) * 64, (x >> 4) * 64, psm);
  } else {
    int x = bid - 9216;
    if (x < 2) pos_seg_body(mq, nullptr, posq, vq, nullptr, 2048, 0, x, psm);
    else       pos_seg_body(mkv, dists, posk, kbias, dtok, 2048, 1, x - 2, psm);
  }
}

// ================= MFMA GEMM body (BK=64, single-buffered) =================
union GemmSmem {
  struct { u16 As[128 * 64]; u16 Bs[128 * 64]; } st;
  u16 tr[4][64 * 72];                 // MODE1 V-transpose epilogue buffers
};

template<int MODE>
__device__ void gemm_body(GemmSmem& sm,
    const u16* __restrict__ A, const u16* __restrict__ WT, const float* __restrict__ bias,
    int M, int N, int K, const float* __restrict__ pos, const float* __restrict__ dist,
    int bx, int by, u16* __restrict__ outA, u16* __restrict__ outB, float* __restrict__ outF)
{
  const int rowbase = by * 128;
  const int colbase = bx * 128;
  const int tid = threadIdx.x;
  const int lane = tid & 63, wv = tid >> 6;
  const int wr = wv >> 1, wc = wv & 1;
  const int l15 = lane & 15, l4 = lane >> 4;
  const int l8r = lane >> 3;                // row-within-8 for staging
  const int sjc = (lane & 7) ^ l8r;         // swizzled source chunk (involution)
  f32x4 acc[4][4] = {};
  for (int kt = 0; kt < K; kt += 64) {
    __syncthreads();
#pragma unroll
    for (int i = 0; i < 4; i++) {
      int rg = (wv * 4 + i) * 8 + l8r;      // 0..127
      gload16(A  + (size_t)(rowbase + rg) * K + kt + sjc * 8, &sm.st.As[(wv * 4 + i) * 512]);
      gload16(WT + (size_t)(colbase + rg) * K + kt + sjc * 8, &sm.st.Bs[(wv * 4 + i) * 512]);
    }
    __syncthreads();
#pragma unroll
    for (int kk = 0; kk < 2; kk++) {
      bf16x8 af[4], bfr[4];
      const int fsw = l15 & 7;
#pragma unroll
      for (int m = 0; m < 4; m++)
        af[m] = *(const bf16x8*)&sm.st.As[(wr * 64 + m * 16 + l15) * 64 + (((kk * 4 + l4) ^ fsw) * 8)];
#pragma unroll
      for (int n = 0; n < 4; n++)
        bfr[n] = *(const bf16x8*)&sm.st.Bs[(wc * 64 + n * 16 + l15) * 64 + (((kk * 4 + l4) ^ fsw) * 8)];
#pragma unroll
      for (int m = 0; m < 4; m++)
#pragma unroll
        for (int n = 0; n < 4; n++)
          acc[m][n] = __builtin_amdgcn_mfma_f32_16x16x32_bf16(af[m], bfr[n], acc[m][n], 0, 0, 0);
    }
  }
  __syncthreads();

  if constexpr (MODE == 2) {
#pragma unroll
    for (int n = 0; n < 4; n++) {
      float bv = bias[colbase + wc * 64 + n * 16 + l15];
#pragma unroll
      for (int m = 0; m < 4; m++)
#pragma unroll
        for (int r = 0; r < 4; r++) {
          int grow = rowbase + wr * 64 + m * 16 + l4 * 4 + r;
          outF[(size_t)grow * N + colbase + wc * 64 + n * 16 + l15] = acc[m][n][r] + bv;
        }
    }
  } else if constexpr (MODE == 0) {
    const int b = rowbase >> 11;
    const int h = (colbase + wc * 64) >> 6;
    const float if0 = __powf(10000.0f, -(float)l15 / 32.0f);
    const float if1 = __powf(10000.0f, -(float)(16 + l15) / 32.0f);
    const float b0 = bias[colbase + wc * 64 + l15];
    const float b1 = bias[colbase + wc * 64 + 16 + l15];
    const float b2 = bias[colbase + wc * 64 + 32 + l15];
    const float b3 = bias[colbase + wc * 64 + 48 + l15];
    // 0.125 * log2(e): attn uses raw v_exp_f32 (2^x); scaling commutes with RoPE
    const float QS2 = 0.18033688f;
#pragma unroll
    for (int m = 0; m < 4; m++) {
#pragma unroll
      for (int r = 0; r < 4; r++) {
        int grow = rowbase + wr * 64 + m * 16 + l4 * 4 + r;
        int tok = grow & 2047;
        float pv = pos[grow];
        float s0, c0, s1, c1;
        __sincosf(pv * if0, &s0, &c0);
        __sincosf(pv * if1, &s1, &c1);
        float x0 = (acc[m][0][r] + b0) * QS2;
        float x1 = (acc[m][1][r] + b1) * QS2;
        float x2 = (acc[m][2][r] + b2) * QS2;
        float x3 = (acc[m][3][r] + b3) * QS2;
        size_t ob = (((size_t)b * CNH + h) * CLQ + tok) * CHD;
        outA[ob + l15]      = f2bf(x0 * c0 - x2 * s0);
        outA[ob + 32 + l15] = f2bf(x2 * c0 + x0 * s0);
        outA[ob + 16 + l15] = f2bf(x1 * c1 - x3 * s1);
        outA[ob + 48 + l15] = f2bf(x3 * c1 + x1 * s1);
      }
    }
  } else {  // MODE 1
    const int b = rowbase >> 11;
    if (colbase < CHID) {   // K half
      const int h = (colbase + wc * 64) >> 6;
      const float if0 = __powf(10000.0f, -(float)l15 / 32.0f);
      const float if1 = __powf(10000.0f, -(float)(16 + l15) / 32.0f);
      const float df0 = __expf(-11.5129254f + 0.32666551f * (float)l15);
      const float df1 = __expf(-11.5129254f + 0.32666551f * (float)(16 + l15));
      const float b0 = bias[colbase + wc * 64 + l15];
      const float b1 = bias[colbase + wc * 64 + 16 + l15];
      const float b2 = bias[colbase + wc * 64 + 32 + l15];
      const float b3 = bias[colbase + wc * 64 + 48 + l15];
#pragma unroll
      for (int m = 0; m < 4; m++) {
#pragma unroll
        for (int r = 0; r < 4; r++) {
          int grow = rowbase + wr * 64 + m * 16 + l4 * 4 + r;
          int tok = grow & 2047;
          float pv = pos[grow];
          float dv = dist[grow];
          float s0, c0, s1, c1, ds0, dc0, ds1, dc1;
          __sincosf(pv * if0, &s0, &c0);
          __sincosf(pv * if1, &s1, &c1);
          __sincosf(dv * df0, &ds0, &dc0);
          __sincosf(dv * df1, &ds1, &dc1);
          float x0 = acc[m][0][r] + b0;
          float x1 = acc[m][1][r] + b1;
          float x2 = acc[m][2][r] + b2;
          float x3 = acc[m][3][r] + b3;
          size_t ob = (((size_t)b * CNH + h) * CLK + tok) * CHD;
          outA[ob + l15]      = f2bf(x0 * c0 - x2 * s0 + dc0);
          outA[ob + 32 + l15] = f2bf(x2 * c0 + x0 * s0 + ds0);
          outA[ob + 16 + l15] = f2bf(x1 * c1 - x3 * s1 + dc1);
          outA[ob + 48 + l15] = f2bf(x3 * c1 + x1 * s1 + ds1);
        }
      }
    } else {                // V half -> write transposed [B,NH,HD,LK]
      const int h = (colbase + wc * 64 - CHID) >> 6;
      const int tokb = (rowbase & 2047) + wr * 64;
      u16* T = sm.tr[wv];
#pragma unroll
      for (int n = 0; n < 4; n++) {
        float bv = bias[colbase + wc * 64 + n * 16 + l15];
#pragma unroll
        for (int m = 0; m < 4; m++)
#pragma unroll
          for (int r = 0; r < 4; r++)
            T[(n * 16 + l15) * 72 + m * 16 + l4 * 4 + r] = f2bf(acc[m][n][r] + bv);
      }
#pragma unroll
      for (int p = 0; p < 8; p++) {
        int c = p * 64 + lane;
        int hd = c >> 3, to = (c & 7) * 8;
        *(bf16x8*)(outB + (((size_t)b * CNH + h) * CHD + hd) * CLK + tokb + to) =
            *(const bf16x8*)&T[hd * 72 + to];
      }
    }
  }
}

// fused qproj + kvproj: grid (24, 32); bx<8 -> qproj col bx, else kvproj col bx-8
__global__ __launch_bounds__(256) void qkv_kernel(
    const u16* QS, const u16* WqT, const float* bq, const float* posq,
    const u16* KVS, const u16* WkvT, const float* bkv, const float* posk, const float* dtok,
    u16* QROT, u16* KROT, u16* VT)
{
  __shared__ __align__(16) GemmSmem sm;
  if (blockIdx.x < 8)
    gemm_body<0>(sm, QS, WqT, bq, 4096, 1024, 1024, posq, nullptr,
                 blockIdx.x, blockIdx.y, QROT, nullptr, nullptr);
  else
    gemm_body<1>(sm, KVS, WkvT, bkv, 4096, 2048, 1024, posk, dtok,
                 blockIdx.x - 8, blockIdx.y, KROT, VT, nullptr);
}

__global__ __launch_bounds__(256) void oproj_kernel(
    const u16* AOUT, const u16* WoT, const float* bo, float* out)
{
  __shared__ __align__(16) GemmSmem sm;
  gemm_body<2>(sm, AOUT, WoT, bo, 4096, 1024, 1024, nullptr, nullptr,
               blockIdx.x, blockIdx.y, nullptr, nullptr, out);
}

// ---------------- flash attention (R11-exact + raw v_exp_f32 softmax) ----------------
// 4 waves x 32 q-rows (QBLK 128), grid (16,16,2), double-buffered gload_lds
// staging, u32-typed fenced P-bounce at 288B stride. Only delta vs R11:
// p = v_exp_f32(z + kb) with log2e pre-folded into the Q projection scale
// (saves 16 v_mul per tile per m; identical math to R11's __expf).
__global__ __launch_bounds__(256) void attn_kernel(
    const u16* __restrict__ qr, const u16* __restrict__ kr, const u16* __restrict__ vt,
    const float* __restrict__ kbias, const float* __restrict__ validq,
    u16* __restrict__ aout)
{
  __shared__ __align__(16) u16 Ks[2][64 * 64];       // [tok][hd], swizzled 128B rows
  __shared__ __align__(16) u16 Vs[2][64 * 64];       // [hd][tok], swizzled 128B rows
  __shared__ __align__(16) uint32_t Pb32[4][592];    // per-wave P^T bounce (u32-typed)
  const int qb = blockIdx.x * 128;
  const int h = blockIdx.y, b = blockIdx.z;
  const int tid = threadIdx.x, lane = tid & 63, wv = tid >> 6;
  const int l15 = lane & 15, l4 = lane >> 4;
  const u16* kg = kr + ((size_t)b * CNH + h) * CLK * CHD;
  const u16* vg = vt + ((size_t)b * CNH + h) * CHD * CLK;
  const float* kb_b = kbias + (size_t)b * CLK;
  const int qrow0 = qb + wv * 32;
  const u16* qg = qr + (((size_t)b * CNH + h) * CLQ + qrow0) * CHD;

  bf16x8 qf[2][2];
#pragma unroll
  for (int m = 0; m < 2; m++)
#pragma unroll
    for (int hc = 0; hc < 2; hc++)
      qf[m][hc] = *(const bf16x8*)(qg + (m * 16 + l15) * CHD + hc * 32 + l4 * 8);

  const int srow = lane >> 3;               // 0..7 (row within 1KB region)
  const int sj = (lane & 7) ^ srow;         // swizzled source chunk
  f32x4 accO[2][4] = {};
  float lReg[2] = {0.f, 0.f};
  uint32_t* PbW = Pb32[wv];

  auto stage = [&](int buf, int kt) {
#pragma unroll
    for (int i = 0; i < 2; i++) {
      int r = (wv * 2 + i) * 8 + srow;
      gload16(kg + (size_t)(kt + r) * CHD + sj * 8, &Ks[buf][(wv * 2 + i) * 512]);
      gload16(vg + (size_t)r * CLK + kt + sj * 8,   &Vs[buf][(wv * 2 + i) * 512]);
    }
  };

  stage(0, 0);
  __syncthreads();
  for (int t = 0; t < CLK / 64; t++) {
    const int cur = t & 1;
    if (t < CLK / 64 - 1) stage(cur ^ 1, (t + 1) * 64);
    const u16* Kc = Ks[cur];
    const u16* Vc = Vs[cur];
    const int fsw = l15 & 7;
    float4 kb4[4];
#pragma unroll
    for (int c = 0; c < 4; c++)
      kb4[c] = *(const float4*)(kb_b + t * 64 + c * 16 + l4 * 4);
    bf16x8 kf[4][2], vf[4][2];
#pragma unroll
    for (int c = 0; c < 4; c++)
#pragma unroll
      for (int hc = 0; hc < 2; hc++)
        kf[c][hc] = *(const bf16x8*)&Kc[(c * 16 + l15) * 64 + (((hc * 4 + l4) ^ fsw) * 8)];
#pragma unroll
    for (int hh = 0; hh < 4; hh++)
#pragma unroll
      for (int kc = 0; kc < 2; kc++)
        vf[hh][kc] = *(const bf16x8*)&Vc[(hh * 16 + l15) * 64 + (((kc * 4 + l4) ^ fsw) * 8)];
#pragma unroll
    for (int m = 0; m < 2; m++) {
      // S^T = K @ Q : lane owns q=l15, kv = c*16 + l4*4 + r
      float p[16];
#pragma unroll
      for (int c = 0; c < 4; c++) {
        f32x4 z = {};
        z = __builtin_amdgcn_mfma_f32_16x16x32_bf16(kf[c][0], qf[m][0], z, 0, 0, 0);
        z = __builtin_amdgcn_mfma_f32_16x16x32_bf16(kf[c][1], qf[m][1], z, 0, 0, 0);
        const float* kbp = (const float*)&kb4[c];
#pragma unroll
        for (int r = 0; r < 4; r++)
          p[c * 4 + r] = fexp2(z[r] + kbp[r]);   // log2e pre-folded into Q
      }
      lReg[m] += (((p[0] + p[1]) + (p[2] + p[3])) + ((p[4] + p[5]) + (p[6] + p[7]))) +
                 (((p[8] + p[9]) + (p[10] + p[11])) + ((p[12] + p[13]) + (p[14] + p[15])));
      // pack P^T in PV B-frag order: kv-block t8 at bijective 288B (=72 u32) stride
      const int wbase = 2 * (l4 & 1);
      asm volatile("" ::: "memory");
#pragma unroll
      for (int c = 0; c < 4; c++) {
        int t8 = 2 * c + (l4 >> 1);
#pragma unroll
        for (int rr = 0; rr < 2; rr++)
          PbW[t8 * 72 + l15 * 4 + wbase + rr] = cvtpk(p[c * 4 + 2 * rr], p[c * 4 + 2 * rr + 1]);
      }
      asm volatile("" ::: "memory");
      u4bf8 plo, phi;
      plo.u = *(const uint4*)&PbW[l4 * 72 + l15 * 4];
      phi.u = *(const uint4*)&PbW[288 + l4 * 72 + l15 * 4];
#pragma unroll
      for (int hh = 0; hh < 4; hh++) {
        accO[m][hh] = __builtin_amdgcn_mfma_f32_16x16x32_bf16(vf[hh][0], plo.v, accO[m][hh], 0, 0, 0);
        accO[m][hh] = __builtin_amdgcn_mfma_f32_16x16x32_bf16(vf[hh][1], phi.v, accO[m][hh], 0, 0, 0);
      }
      asm volatile("" ::: "memory");
    }
    __syncthreads();
  }

  // epilogue: normalize, bounce through LDS (u32-typed) for coalesced stores
#pragma unroll
  for (int m = 0; m < 2; m++) {
    float lq = lReg[m];
    lq += __shfl_xor(lq, 16);
    lq += __shfl_xor(lq, 32);
    float inv = validq[(size_t)b * CLQ + qrow0 + m * 16 + l15] / lq;
    asm volatile("" ::: "memory");
#pragma unroll
    for (int hh = 0; hh < 4; hh++)
#pragma unroll
      for (int rr = 0; rr < 2; rr++)
        PbW[l15 * 36 + hh * 8 + l4 * 2 + rr] =
            cvtpk(accO[m][hh][2 * rr] * inv, accO[m][hh][2 * rr + 1] * inv);
    asm volatile("" ::: "memory");
#pragma unroll
    for (int i = 0; i < 2; i++) {
      int row = i * 8 + (lane >> 3), ch = lane & 7;
      u4bf8 ov;
      ov.u = *(const uint4*)&PbW[row * 36 + ch * 4];
      *(bf16x8*)(aout + ((size_t)b * CLQ + qrow0 + m * 16 + row) * CHID + h * CHD + ch * 8) = ov.v;
    }
    asm volatile("" ::: "memory");
  }
}

extern "C" void kernel_launch(void* const* d_in, const int* in_sizes, int n_in,
                              void* d_out, int out_size, void* d_ws, size_t ws_size,
                              hipStream_t stream)
{
  const float* q_states  = (const float*)d_in[0];
  const float* kv_states = (const float*)d_in[1];
  const float* dists     = (const float*)d_in[2];
  const int*   mq        = (const int*)d_in[3];
  const int*   mkv       = (const int*)d_in[4];
  const float* Wq        = (const float*)d_in[5];
  const float* bq        = (const float*)d_in[6];
  const float* Wkv       = (const float*)d_in[7];
  const float* bkv       = (const float*)d_in[8];
  const float* Wo        = (const float*)d_in[9];
  const float* bo        = (const float*)d_in[10];
  float* out = (float*)d_out;

  char* w = (char*)d_ws;
  auto alloc = [&](size_t bytes) {
    char* p = w;
    w += (bytes + 255) & ~(size_t)255;
    return p;
  };
  u16* WqT  = (u16*)alloc((size_t)1024 * 1024 * 2);
  u16* WkvT = (u16*)alloc((size_t)2048 * 1024 * 2);
  u16* WoT  = (u16*)alloc((size_t)1024 * 1024 * 2);
  u16* QS   = (u16*)alloc((size_t)4096 * 1024 * 2);
  u16* KVS  = (u16*)alloc((size_t)4096 * 1024 * 2);
  u16* QROT = (u16*)alloc((size_t)4096 * 1024 * 2);
  u16* KROT = (u16*)alloc((size_t)4096 * 1024 * 2);
  u16* VT   = (u16*)alloc((size_t)4096 * 1024 * 2);
  u16* AOUT = (u16*)alloc((size_t)4096 * 1024 * 2);
  float* posq  = (float*)alloc(4096 * 4);
  float* vq    = (float*)alloc(4096 * 4);
  float* posk  = (float*)alloc(4096 * 4);
  float* kbias = (float*)alloc(4096 * 4);
  float* dtok  = (float*)alloc(4096 * 4);

  prep_kernel<<<9220, 256, 0, stream>>>(q_states, kv_states, Wq, Wkv, Wo,
                                        mq, mkv, dists,
                                        QS, KVS, WqT, WkvT, WoT,
                                        posq, vq, posk, kbias, dtok);
  qkv_kernel<<<dim3(24, 32), 256, 0, stream>>>(QS, WqT, bq, posq,
                                               KVS, WkvT, bkv, posk, dtok,
                                               QROT, KROT, VT);
  attn_kernel<<<dim3(16, 16, 2), 256, 0, stream>>>(QROT, KROT, VT, kbias, vq, AOUT);
  oproj_kernel<<<dim3(8, 32), 256, 0, stream>>>(AOUT, WoT, bo, out);
}

// Round 18
// 145.868 us; speedup vs baseline: 1.2198x; 1.0364x over previous
//
#include <hip/hip_runtime.h>
#include <stdint.h>

typedef unsigned short u16;
typedef __bf16 bf16x8 __attribute__((ext_vector_type(8)));
typedef float f32x4 __attribute__((ext_vector_type(4)));

#define CB   2
#define CLQ  2048
#define CLK  2048
#define CHID 1024
#define CNH  16
#define CHD  64

__device__ __forceinline__ u16 f2bf(float x) {
  union { float f; uint32_t u; } c; c.f = x;
  uint32_t r = c.u + 0x7FFFu + ((c.u >> 16) & 1u);
  return (u16)(r >> 16);
}

__device__ __forceinline__ uint32_t cvtpk(float lo, float hi) {
  uint32_t r;
  asm("v_cvt_pk_bf16_f32 %0, %1, %2" : "=v"(r) : "v"(lo), "v"(hi));
  return r;
}

__device__ __forceinline__ float fexp2(float x) {   // raw v_exp_f32 (2^x), fast path
  float r;
  asm("v_exp_f32 %0, %1" : "=v"(r) : "v"(x));
  return r;
}

union u4bf8 { uint4 u; bf16x8 v; };

typedef __attribute__((address_space(3))) uint32_t lds_u32;
typedef const __attribute__((address_space(1))) uint32_t glb_u32;
__device__ __forceinline__ void gload16(const void* g, void* l) {
  __builtin_amdgcn_global_load_lds((glb_u32*)g, (lds_u32*)l, 16, 0, 0);
}

// ================= prep megakernel bodies =================
union PrepSmem {
  float t[64][65];
  struct { int bnd[2048]; int part[256]; } ps;
};

__device__ void cvt_body(const float* __restrict__ in, u16* __restrict__ out, int bid) {
  int i = (bid * 256 + (int)threadIdx.x) * 4;
  float4 v = *(const float4*)(in + i);
  ushort4 o;
  o.x = f2bf(v.x); o.y = f2bf(v.y); o.z = f2bf(v.z); o.w = f2bf(v.w);
  *(ushort4*)(out + i) = o;
}

__device__ void wtrans_body(const float* __restrict__ W, u16* __restrict__ WT,
                            int K, int N, int nb, int kb, PrepSmem& sm) {
  const int tx = threadIdx.x & 63, ty = threadIdx.x >> 6;
#pragma unroll
  for (int i = 0; i < 16; i++) {
    int r = i * 4 + ty;
    sm.t[r][tx] = W[(size_t)(kb + r) * N + nb + tx];
  }
  __syncthreads();
#pragma unroll
  for (int i = 0; i < 16; i++) {
    int r = i * 4 + ty;
    WT[(size_t)(nb + r) * K + kb + tx] = f2bf(sm.t[tx][r]);
  }
}

__device__ void pos_seg_body(const int* __restrict__ lengths, const float* __restrict__ dists,
                             float* __restrict__ pos, float* __restrict__ maskv,
                             float* __restrict__ distout, int L, int isKV, int b, PrepSmem& sm) {
  const int tid = threadIdx.x;
  const int* len = lengths + (size_t)b * L;
  int loc[8];
  const int base = tid * 8;
  int s = 0;
#pragma unroll
  for (int i = 0; i < 8; i++) { loc[i] = len[base + i]; s += loc[i]; }
  sm.ps.part[tid] = s;
  __syncthreads();
  for (int off = 1; off < 256; off <<= 1) {
    int v = sm.ps.part[tid];
    int add = (tid >= off) ? sm.ps.part[tid - off] : 0;
    __syncthreads();
    sm.ps.part[tid] = v + add;
    __syncthreads();
  }
  int run = (tid > 0) ? sm.ps.part[tid - 1] : 0;
#pragma unroll
  for (int i = 0; i < 8; i++) { run += loc[i]; sm.ps.bnd[base + i] = run; }
  __syncthreads();
  const int total = sm.ps.bnd[L - 1];
  for (int t = tid; t < L; t += 256) {
    int lo = 0, hi = L;
    while (lo < hi) { int mid = (lo + hi) >> 1; if (sm.ps.bnd[mid] <= t) lo = mid + 1; else hi = mid; }
    int seg = lo < L - 1 ? lo : L - 1;
    int start = sm.ps.bnd[seg] - len[seg];
    bool valid = t < total;
    pos[(size_t)b * L + t] = valid ? (float)(t - start) : 0.0f;
    if (isKV) {
      maskv[(size_t)b * L + t] = valid ? 0.0f : -1e9f;
      distout[(size_t)b * L + t] = valid ? dists[(size_t)b * L + seg] : 0.0f;
    } else {
      maskv[(size_t)b * L + t] = valid ? 1.0f : 0.0f;
    }
  }
}

// grid 9220: [0,4096) cvt QS | [4096,8192) cvt KVS | [8192,8448) wtrans Wq |
// [8448,8960) wtrans Wkv | [8960,9216) wtrans Wo | [9216,9220) pos_seg
__global__ __launch_bounds__(256) void prep_kernel(
    const float* q_states, const float* kv_states,
    const float* Wq, const float* Wkv, const float* Wo,
    const int* mq, const int* mkv, const float* dists,
    u16* QS, u16* KVS, u16* WqT, u16* WkvT, u16* WoT,
    float* posq, float* vq, float* posk, float* kbias, float* dtok)
{
  __shared__ PrepSmem psm;
  const int bid = blockIdx.x;
  if (bid < 4096) {
    cvt_body(q_states, QS, bid);
  } else if (bid < 8192) {
    cvt_body(kv_states, KVS, bid - 4096);
  } else if (bid < 8448) {
    int x = bid - 8192;
    wtrans_body(Wq, WqT, 1024, 1024, (x & 15) * 64, (x >> 4) * 64, psm);
  } else if (bid < 8960) {
    int x = bid - 8448;
    wtrans_body(Wkv, WkvT, 1024, 2048, (x & 31) * 64, (x >> 5) * 64, psm);
  } else if (bid < 9216) {
    int x = bid - 8960;
    wtrans_body(Wo, WoT, 1024, 1024, (x & 15) * 64, (x >> 4) * 64, psm);
  } else {
    int x = bid - 9216;
    if (x < 2) pos_seg_body(mq, nullptr, posq, vq, nullptr, 2048, 0, x, psm);
    else       pos_seg_body(mkv, dists, posk, kbias, dtok, 2048, 1, x - 2, psm);
  }
}

// ================= MFMA GEMM body (BK=64, single-buffered) =================
// MR = per-wave m-repeat: tile is (MR*32) rows x 128 cols. MR=4 -> 128x128
// (qkv, R11-proven); MR=2 -> 64x128 (oproj: doubles blocks/CU to 2).
union GemmSmem {
  struct { u16 As[128 * 64]; u16 Bs[128 * 64]; } st;
  u16 tr[4][64 * 72];                 // MODE1 V-transpose epilogue buffers
};

template<int MODE, int MR>
__device__ void gemm_body(GemmSmem& sm,
    const u16* __restrict__ A, const u16* __restrict__ WT, const float* __restrict__ bias,
    int M, int N, int K, const float* __restrict__ pos, const float* __restrict__ dist,
    int bx, int by, u16* __restrict__ outA, u16* __restrict__ outB, float* __restrict__ outF)
{
  const int rowbase = by * (MR * 32);
  const int colbase = bx * 128;
  const int tid = threadIdx.x;
  const int lane = tid & 63, wv = tid >> 6;
  const int wr = wv >> 1, wc = wv & 1;
  const int l15 = lane & 15, l4 = lane >> 4;
  const int l8r = lane >> 3;                // row-within-8 for staging
  const int sjc = (lane & 7) ^ l8r;         // swizzled source chunk (involution)
  f32x4 acc[MR][4] = {};
  for (int kt = 0; kt < K; kt += 64) {
    __syncthreads();
#pragma unroll
    for (int i = 0; i < MR; i++) {          // A: MR regions per wave (tile rows = MR*32)
      int rg = (wv * MR + i) * 8 + l8r;
      gload16(A + (size_t)(rowbase + rg) * K + kt + sjc * 8, &sm.st.As[(wv * MR + i) * 512]);
    }
#pragma unroll
    for (int i = 0; i < 4; i++) {           // B: 16 regions (128 cols)
      int rg = (wv * 4 + i) * 8 + l8r;
      gload16(WT + (size_t)(colbase + rg) * K + kt + sjc * 8, &sm.st.Bs[(wv * 4 + i) * 512]);
    }
    __syncthreads();
#pragma unroll
    for (int kk = 0; kk < 2; kk++) {
      bf16x8 af[MR], bfr[4];
      const int fsw = l15 & 7;
#pragma unroll
      for (int m = 0; m < MR; m++)
        af[m] = *(const bf16x8*)&sm.st.As[(wr * (MR * 16) + m * 16 + l15) * 64 + (((kk * 4 + l4) ^ fsw) * 8)];
#pragma unroll
      for (int n = 0; n < 4; n++)
        bfr[n] = *(const bf16x8*)&sm.st.Bs[(wc * 64 + n * 16 + l15) * 64 + (((kk * 4 + l4) ^ fsw) * 8)];
#pragma unroll
      for (int m = 0; m < MR; m++)
#pragma unroll
        for (int n = 0; n < 4; n++)
          acc[m][n] = __builtin_amdgcn_mfma_f32_16x16x32_bf16(af[m], bfr[n], acc[m][n], 0, 0, 0);
    }
  }
  __syncthreads();

  if constexpr (MODE == 2) {
#pragma unroll
    for (int n = 0; n < 4; n++) {
      float bv = bias[colbase + wc * 64 + n * 16 + l15];
#pragma unroll
      for (int m = 0; m < MR; m++)
#pragma unroll
        for (int r = 0; r < 4; r++) {
          int grow = rowbase + wr * (MR * 16) + m * 16 + l4 * 4 + r;
          outF[(size_t)grow * N + colbase + wc * 64 + n * 16 + l15] = acc[m][n][r] + bv;
        }
    }
  } else if constexpr (MODE == 0) {
    const int b = rowbase >> 11;
    const int h = (colbase + wc * 64) >> 6;
    const float if0 = __powf(10000.0f, -(float)l15 / 32.0f);
    const float if1 = __powf(10000.0f, -(float)(16 + l15) / 32.0f);
    const float b0 = bias[colbase + wc * 64 + l15];
    const float b1 = bias[colbase + wc * 64 + 16 + l15];
    const float b2 = bias[colbase + wc * 64 + 32 + l15];
    const float b3 = bias[colbase + wc * 64 + 48 + l15];
    // 0.125 * log2(e): attn uses raw v_exp_f32 (2^x); scaling commutes with RoPE
    const float QS2 = 0.18033688f;
#pragma unroll
    for (int m = 0; m < MR; m++) {
#pragma unroll
      for (int r = 0; r < 4; r++) {
        int grow = rowbase + wr * (MR * 16) + m * 16 + l4 * 4 + r;
        int tok = grow & 2047;
        float pv = pos[grow];
        float s0, c0, s1, c1;
        __sincosf(pv * if0, &s0, &c0);
        __sincosf(pv * if1, &s1, &c1);
        float x0 = (acc[m][0][r] + b0) * QS2;
        float x1 = (acc[m][1][r] + b1) * QS2;
        float x2 = (acc[m][2][r] + b2) * QS2;
        float x3 = (acc[m][3][r] + b3) * QS2;
        size_t ob = (((size_t)b * CNH + h) * CLQ + tok) * CHD;
        outA[ob + l15]      = f2bf(x0 * c0 - x2 * s0);
        outA[ob + 32 + l15] = f2bf(x2 * c0 + x0 * s0);
        outA[ob + 16 + l15] = f2bf(x1 * c1 - x3 * s1);
        outA[ob + 48 + l15] = f2bf(x3 * c1 + x1 * s1);
      }
    }
  } else {  // MODE 1
    const int b = rowbase >> 11;
    if (colbase < CHID) {   // K half
      const int h = (colbase + wc * 64) >> 6;
      const float if0 = __powf(10000.0f, -(float)l15 / 32.0f);
      const float if1 = __powf(10000.0f, -(float)(16 + l15) / 32.0f);
      const float df0 = __expf(-11.5129254f + 0.32666551f * (float)l15);
      const float df1 = __expf(-11.5129254f + 0.32666551f * (float)(16 + l15));
      const float b0 = bias[colbase + wc * 64 + l15];
      const float b1 = bias[colbase + wc * 64 + 16 + l15];
      const float b2 = bias[colbase + wc * 64 + 32 + l15];
      const float b3 = bias[colbase + wc * 64 + 48 + l15];
#pragma unroll
      for (int m = 0; m < MR; m++) {
#pragma unroll
        for (int r = 0; r < 4; r++) {
          int grow = rowbase + wr * (MR * 16) + m * 16 + l4 * 4 + r;
          int tok = grow & 2047;
          float pv = pos[grow];
          float dv = dist[grow];
          float s0, c0, s1, c1, ds0, dc0, ds1, dc1;
          __sincosf(pv * if0, &s0, &c0);
          __sincosf(pv * if1, &s1, &c1);
          __sincosf(dv * df0, &ds0, &dc0);
          __sincosf(dv * df1, &ds1, &dc1);
          float x0 = acc[m][0][r] + b0;
          float x1 = acc[m][1][r] + b1;
          float x2 = acc[m][2][r] + b2;
          float x3 = acc[m][3][r] + b3;
          size_t ob = (((size_t)b * CNH + h) * CLK + tok) * CHD;
          outA[ob + l15]      = f2bf(x0 * c0 - x2 * s0 + dc0);
          outA[ob + 32 + l15] = f2bf(x2 * c0 + x0 * s0 + ds0);
          outA[ob + 16 + l15] = f2bf(x1 * c1 - x3 * s1 + dc1);
          outA[ob + 48 + l15] = f2bf(x3 * c1 + x1 * s1 + ds1);
        }
      }
    } else {                // V half -> write transposed [B,NH,HD,LK]  (MR==4 only)
      const int h = (colbase + wc * 64 - CHID) >> 6;
      const int tokb = (rowbase & 2047) + wr * (MR * 16);
      u16* T = sm.tr[wv];
#pragma unroll
      for (int n = 0; n < 4; n++) {
        float bv = bias[colbase + wc * 64 + n * 16 + l15];
#pragma unroll
        for (int m = 0; m < MR; m++)
#pragma unroll
          for (int r = 0; r < 4; r++)
            T[(n * 16 + l15) * 72 + m * 16 + l4 * 4 + r] = f2bf(acc[m][n][r] + bv);
      }
#pragma unroll
      for (int p = 0; p < 8; p++) {
        int c = p * 64 + lane;
        int hd = c >> 3, to = (c & 7) * 8;
        *(bf16x8*)(outB + (((size_t)b * CNH + h) * CHD + hd) * CLK + tokb + to) =
            *(const bf16x8*)&T[hd * 72 + to];
      }
    }
  }
}

// fused qproj + kvproj: grid (24, 32); bx<8 -> qproj col bx, else kvproj col bx-8
__global__ __launch_bounds__(256) void qkv_kernel(
    const u16* QS, const u16* WqT, const float* bq, const float* posq,
    const u16* KVS, const u16* WkvT, const float* bkv, const float* posk, const float* dtok,
    u16* QROT, u16* KROT, u16* VT)
{
  __shared__ __align__(16) GemmSmem sm;
  if (blockIdx.x < 8)
    gemm_body<0, 4>(sm, QS, WqT, bq, 4096, 1024, 1024, posq, nullptr,
                    blockIdx.x, blockIdx.y, QROT, nullptr, nullptr);
  else
    gemm_body<1, 4>(sm, KVS, WkvT, bkv, 4096, 2048, 1024, posk, dtok,
                    blockIdx.x - 8, blockIdx.y, KROT, VT, nullptr);
}

// oproj: 64-row tiles (MR=2), grid (8, 64) = 512 blocks = 2 blocks/CU
__global__ __launch_bounds__(256) void oproj_kernel(
    const u16* AOUT, const u16* WoT, const float* bo, float* out)
{
  __shared__ __align__(16) GemmSmem sm;
  gemm_body<2, 2>(sm, AOUT, WoT, bo, 4096, 1024, 1024, nullptr, nullptr,
                  blockIdx.x, blockIdx.y, nullptr, nullptr, out);
}

// ---------------- flash attention (byte-identical to passing R17) ----------------
__global__ __launch_bounds__(256) void attn_kernel(
    const u16* __restrict__ qr, const u16* __restrict__ kr, const u16* __restrict__ vt,
    const float* __restrict__ kbias, const float* __restrict__ validq,
    u16* __restrict__ aout)
{
  __shared__ __align__(16) u16 Ks[2][64 * 64];       // [tok][hd], swizzled 128B rows
  __shared__ __align__(16) u16 Vs[2][64 * 64];       // [hd][tok], swizzled 128B rows
  __shared__ __align__(16) uint32_t Pb32[4][592];    // per-wave P^T bounce (u32-typed)
  const int qb = blockIdx.x * 128;
  const int h = blockIdx.y, b = blockIdx.z;
  const int tid = threadIdx.x, lane = tid & 63, wv = tid >> 6;
  const int l15 = lane & 15, l4 = lane >> 4;
  const u16* kg = kr + ((size_t)b * CNH + h) * CLK * CHD;
  const u16* vg = vt + ((size_t)b * CNH + h) * CHD * CLK;
  const float* kb_b = kbias + (size_t)b * CLK;
  const int qrow0 = qb + wv * 32;
  const u16* qg = qr + (((size_t)b * CNH + h) * CLQ + qrow0) * CHD;

  bf16x8 qf[2][2];
#pragma unroll
  for (int m = 0; m < 2; m++)
#pragma unroll
    for (int hc = 0; hc < 2; hc++)
      qf[m][hc] = *(const bf16x8*)(qg + (m * 16 + l15) * CHD + hc * 32 + l4 * 8);

  const int srow = lane >> 3;               // 0..7 (row within 1KB region)
  const int sj = (lane & 7) ^ srow;         // swizzled source chunk
  f32x4 accO[2][4] = {};
  float lReg[2] = {0.f, 0.f};
  uint32_t* PbW = Pb32[wv];

  auto stage = [&](int buf, int kt) {
#pragma unroll
    for (int i = 0; i < 2; i++) {
      int r = (wv * 2 + i) * 8 + srow;
      gload16(kg + (size_t)(kt + r) * CHD + sj * 8, &Ks[buf][(wv * 2 + i) * 512]);
      gload16(vg + (size_t)r * CLK + kt + sj * 8,   &Vs[buf][(wv * 2 + i) * 512]);
    }
  };

  stage(0, 0);
  __syncthreads();
  for (int t = 0; t < CLK / 64; t++) {
    const int cur = t & 1;
    if (t < CLK / 64 - 1) stage(cur ^ 1, (t + 1) * 64);
    const u16* Kc = Ks[cur];
    const u16* Vc = Vs[cur];
    const int fsw = l15 & 7;
    float4 kb4[4];
#pragma unroll
    for (int c = 0; c < 4; c++)
      kb4[c] = *(const float4*)(kb_b + t * 64 + c * 16 + l4 * 4);
    bf16x8 kf[4][2], vf[4][2];
#pragma unroll
    for (int c = 0; c < 4; c++)
#pragma unroll
      for (int hc = 0; hc < 2; hc++)
        kf[c][hc] = *(const bf16x8*)&Kc[(c * 16 + l15) * 64 + (((hc * 4 + l4) ^ fsw) * 8)];
#pragma unroll
    for (int hh = 0; hh < 4; hh++)
#pragma unroll
      for (int kc = 0; kc < 2; kc++)
        vf[hh][kc] = *(const bf16x8*)&Vc[(hh * 16 + l15) * 64 + (((kc * 4 + l4) ^ fsw) * 8)];
#pragma unroll
    for (int m = 0; m < 2; m++) {
      // S^T = K @ Q : lane owns q=l15, kv = c*16 + l4*4 + r
      float p[16];
#pragma unroll
      for (int c = 0; c < 4; c++) {
        f32x4 z = {};
        z = __builtin_amdgcn_mfma_f32_16x16x32_bf16(kf[c][0], qf[m][0], z, 0, 0, 0);
        z = __builtin_amdgcn_mfma_f32_16x16x32_bf16(kf[c][1], qf[m][1], z, 0, 0, 0);
        const float* kbp = (const float*)&kb4[c];
#pragma unroll
        for (int r = 0; r < 4; r++)
          p[c * 4 + r] = fexp2(z[r] + kbp[r]);   // log2e pre-folded into Q
      }
      lReg[m] += (((p[0] + p[1]) + (p[2] + p[3])) + ((p[4] + p[5]) + (p[6] + p[7]))) +
                 (((p[8] + p[9]) + (p[10] + p[11])) + ((p[12] + p[13]) + (p[14] + p[15])));
      // pack P^T in PV B-frag order: kv-block t8 at bijective 288B (=72 u32) stride
      const int wbase = 2 * (l4 & 1);
      asm volatile("" ::: "memory");
#pragma unroll
      for (int c = 0; c < 4; c++) {
        int t8 = 2 * c + (l4 >> 1);
#pragma unroll
        for (int rr = 0; rr < 2; rr++)
          PbW[t8 * 72 + l15 * 4 + wbase + rr] = cvtpk(p[c * 4 + 2 * rr], p[c * 4 + 2 * rr + 1]);
      }
      asm volatile("" ::: "memory");
      u4bf8 plo, phi;
      plo.u = *(const uint4*)&PbW[l4 * 72 + l15 * 4];
      phi.u = *(const uint4*)&PbW[288 + l4 * 72 + l15 * 4];
#pragma unroll
      for (int hh = 0; hh < 4; hh++) {
        accO[m][hh] = __builtin_amdgcn_mfma_f32_16x16x32_bf16(vf[hh][0], plo.v, accO[m][hh], 0, 0, 0);
        accO[m][hh] = __builtin_amdgcn_mfma_f32_16x16x32_bf16(vf[hh][1], phi.v, accO[m][hh], 0, 0, 0);
      }
      asm volatile("" ::: "memory");
    }
    __syncthreads();
  }

  // epilogue: normalize, bounce through LDS (u32-typed) for coalesced stores
#pragma unroll
  for (int m = 0; m < 2; m++) {
    float lq = lReg[m];
    lq += __shfl_xor(lq, 16);
    lq += __shfl_xor(lq, 32);
    float inv = validq[(size_t)b * CLQ + qrow0 + m * 16 + l15] / lq;
    asm volatile("" ::: "memory");
#pragma unroll
    for (int hh = 0; hh < 4; hh++)
#pragma unroll
      for (int rr = 0; rr < 2; rr++)
        PbW[l15 * 36 + hh * 8 + l4 * 2 + rr] =
            cvtpk(accO[m][hh][2 * rr] * inv, accO[m][hh][2 * rr + 1] * inv);
    asm volatile("" ::: "memory");
#pragma unroll
    for (int i = 0; i < 2; i++) {
      int row = i * 8 + (lane >> 3), ch = lane & 7;
      u4bf8 ov;
      ov.u = *(const uint4*)&PbW[row * 36 + ch * 4];
      *(bf16x8*)(aout + ((size_t)b * CLQ + qrow0 + m * 16 + row) * CHID + h * CHD + ch * 8) = ov.v;
    }
    asm volatile("" ::: "memory");
  }
}

extern "C" void kernel_launch(void* const* d_in, const int* in_sizes, int n_in,
                              void* d_out, int out_size, void* d_ws, size_t ws_size,
                              hipStream_t stream)
{
  const float* q_states  = (const float*)d_in[0];
  const float* kv_states = (const float*)d_in[1];
  const float* dists     = (const float*)d_in[2];
  const int*   mq        = (const int*)d_in[3];
  const int*   mkv       = (const int*)d_in[4];
  const float* Wq        = (const float*)d_in[5];
  const float* bq        = (const float*)d_in[6];
  const float* Wkv       = (const float*)d_in[7];
  const float* bkv       = (const float*)d_in[8];
  const float* Wo        = (const float*)d_in[9];
  const float* bo        = (const float*)d_in[10];
  float* out = (float*)d_out;

  char* w = (char*)d_ws;
  auto alloc = [&](size_t bytes) {
    char* p = w;
    w += (bytes + 255) & ~(size_t)255;
    return p;
  };
  u16* WqT  = (u16*)alloc((size_t)1024 * 1024 * 2);
  u16* WkvT = (u16*)alloc((size_t)2048 * 1024 * 2);
  u16* WoT  = (u16*)alloc((size_t)1024 * 1024 * 2);
  u16* QS   = (u16*)alloc((size_t)4096 * 1024 * 2);
  u16* KVS  = (u16*)alloc((size_t)4096 * 1024 * 2);
  u16* QROT = (u16*)alloc((size_t)4096 * 1024 * 2);
  u16* KROT = (u16*)alloc((size_t)4096 * 1024 * 2);
  u16* VT   = (u16*)alloc((size_t)4096 * 1024 * 2);
  u16* AOUT = (u16*)alloc((size_t)4096 * 1024 * 2);
  float* posq  = (float*)alloc(4096 * 4);
  float* vq    = (float*)alloc(4096 * 4);
  float* posk  = (float*)alloc(4096 * 4);
  float* kbias = (float*)alloc(4096 * 4);
  float* dtok  = (float*)alloc(4096 * 4);

  prep_kernel<<<9220, 256, 0, stream>>>(q_states, kv_states, Wq, Wkv, Wo,
                                        mq, mkv, dists,
                                        QS, KVS, WqT, WkvT, WoT,
                                        posq, vq, posk, kbias, dtok);
  qkv_kernel<<<dim3(24, 32), 256, 0, stream>>>(QS, WqT, bq, posq,
                                               KVS, WkvT, bkv, posk, dtok,
                                               QROT, KROT, VT);
  attn_kernel<<<dim3(16, 16, 2), 256, 0, stream>>>(QROT, KROT, VT, kbias, vq, AOUT);
  oproj_kernel<<<dim3(8, 64), 256, 0, stream>>>(AOUT, WoT, bo, out);
}